// Round 3
// baseline (1749.174 us; speedup 1.0000x reference)
//
#include <hip/hip_runtime.h>
#include <stdint.h>
#include <stddef.h>

typedef float    f32x4  __attribute__((ext_vector_type(4)));
typedef short    bf16x8 __attribute__((ext_vector_type(8)));
typedef uint16_t u16x8  __attribute__((ext_vector_type(8)));
typedef uint32_t u32x4  __attribute__((ext_vector_type(4)));

#define ATT_ROW 136   // 128 data + 8 zero pad (=> 272B rows, 16B aligned)

// ---------- helpers ----------
__device__ __forceinline__ uint16_t f2bf(float x) {
  union { float f; uint32_t u; } c; c.f = x;
  return (uint16_t)((c.u + 0x7FFFu + ((c.u >> 16) & 1u)) >> 16);  // RNE
}
__device__ __forceinline__ float bf2f(uint16_t h) {
  union { uint32_t u; float f; } c; c.u = ((uint32_t)h) << 16;
  return c.f;
}
// XOR swizzle for 64B-row LDS tiles: byte a -> a ^ ((row-bits)<<4). Bijective;
// used consistently on write+read, with explicit inverse in k_prep.
__device__ __forceinline__ int S64s(int a) { return a ^ (((a >> 6) & 7) << 4); }

__device__ __forceinline__ void cp16(void* lds, const void* g) {
  __builtin_amdgcn_global_load_lds((const __attribute__((address_space(1))) void*)g,
                                   (__attribute__((address_space(3))) void*)lds, 16, 0, 0);
}
__device__ __forceinline__ float fast_tanh(float t) {
  float r = __expf(-2.f * t);
  return 1.f - 2.f * r / (1.f + r);
}

// ---------- prep: fc1_W (fp32 [65536][256]) -> bf16 chunked column-major, swizzled ----------
__global__ __launch_bounds__(256) void k_prep(const float* __restrict__ W1,
                                              uint16_t* __restrict__ W1s) {
  __shared__ float st[32 * 256];
  const int c = blockIdx.x, tid = threadIdx.x;
  const float* src = W1 + (size_t)c * 32 * 256;
#pragma unroll
  for (int it = 0; it < 8; ++it) {
    int u = it * 256 + tid;
    ((f32x4*)st)[u] = ((const f32x4*)src)[u];
  }
  __syncthreads();
  uint16_t* dstc = W1s + (size_t)c * 8192;
#pragma unroll
  for (int q = 0; q < 4; ++q) {
    int p  = q * 256 + tid;       // 16B unit 0..1023
    int Np = p >> 2, Gp = p & 3;
    int n  = Np ^ ((Np >> 2) & 1);   // invert S64
    int g  = Gp ^ (n & 3);
    uint32_t w[4];
#pragma unroll
    for (int e2 = 0; e2 < 4; ++e2) {
      uint16_t lo = f2bf(st[(g * 8 + 2 * e2) * 256 + n]);
      uint16_t hi = f2bf(st[(g * 8 + 2 * e2 + 1) * 256 + n]);
      w[e2] = (uint32_t)lo | ((uint32_t)hi << 16);
    }
    u32x4 v; v.x = w[0]; v.y = w[1]; v.z = w[2]; v.w = w[3];
    *(u32x4*)(dstc + (size_t)p * 8) = v;
  }
}

// ---------- attention ----------
__global__ __launch_bounds__(512) void k_att(const float* __restrict__ X,
    const float* __restrict__ aW, const float* __restrict__ aU,
    const float* __restrict__ aV, uint16_t* __restrict__ att) {
  __shared__ float sa[8][8][66];
  __shared__ float su[8][8][66];
  __shared__ float sal[8][64];
  __shared__ float sv[64];
  const int tid = threadIdx.x, lane = tid & 63, w = tid >> 6;
  if (tid < 64) sv[tid] = aV[tid];
  __syncthreads();
  for (int rep = 0; rep < 2; ++rep) {
    int b  = blockIdx.x * 16 + w * 2 + rep;
    int bu = __builtin_amdgcn_readfirstlane(b);
    const float* xb = X + (size_t)bu * 512;
    float xi[8];
#pragma unroll
    for (int i = 0; i < 8; ++i) xi[i] = xb[i * 64 + lane];
    float a[8], u[8];
#pragma unroll
    for (int i = 0; i < 8; ++i) { a[i] = 0.f; u[i] = 0.f; }
#pragma unroll
    for (int f = 0; f < 64; ++f) {
      float wf = aW[f * 64 + lane];
      float uf = aU[f * 64 + lane];
#pragma unroll
      for (int i = 0; i < 8; ++i) {
        float xs = xb[i * 64 + f];      // wave-uniform -> s_load
        a[i] = fmaf(xs, wf, a[i]);
        u[i] = fmaf(xs, uf, u[i]);
      }
    }
#pragma unroll
    for (int i = 0; i < 8; ++i) { sa[w][i][lane] = a[i]; su[w][i][lane] = u[i]; }
    __syncthreads();
    int i2 = lane >> 3, j2 = lane & 7;
    float ev = 0.f;
#pragma unroll
    for (int h = 0; h < 64; ++h)
      ev = fmaf(fast_tanh(sa[w][i2][h] + su[w][j2][h]), sv[h], ev);
    float m = ev;
    m = fmaxf(m, __shfl_xor(m, 1));
    m = fmaxf(m, __shfl_xor(m, 2));
    m = fmaxf(m, __shfl_xor(m, 4));
    float p = __expf(ev - m);
    float s = p;
    s += __shfl_xor(s, 1); s += __shfl_xor(s, 2); s += __shfl_xor(s, 4);
    sal[w][lane] = p / s;
    __syncthreads();
#pragma unroll
    for (int i = 0; i < 8; ++i) {
      float c = 0.f;
#pragma unroll
      for (int j = 0; j < 8; ++j) c = fmaf(sal[w][i * 8 + j], xi[j], c);
      c = fmaf(-sal[w][i * 8 + i], xi[i], c);
      size_t ro = ((size_t)b * 9 + i) * ATT_ROW;
      att[ro + lane]      = f2bf(xi[i]);
      att[ro + 64 + lane] = f2bf(c);
      if (lane < 8) att[ro + 128 + lane] = 0;
    }
    {
      size_t ro = ((size_t)b * 9 + 8) * ATT_ROW;
      att[ro + lane] = 0; att[ro + 64 + lane] = 0;
      if (lane < 8) att[ro + 128 + lane] = 0;
    }
    __syncthreads();
  }
}

// ---------- graph path ----------
__global__ void k_deg(const int* __restrict__ src, const int* __restrict__ dst,
                      float* degO, float* degI) {
  int t = blockIdx.x * 256 + threadIdx.x;
  if (t < 4096) {
    atomicAdd(degO + src[t], 1.f);
    atomicAdd(degI + dst[t], 1.f);
  }
}
__global__ __launch_bounds__(256) void k_gca(const float* __restrict__ h,
    const int* __restrict__ src, const int* __restrict__ dst,
    const float* __restrict__ degO, float* __restrict__ agg) {
  int t = blockIdx.x * 256 + threadIdx.x;   // 4096*128
  int e = t >> 7, d = t & 127;
  int s = src[e];
  float sc = rsqrtf(fmaxf(degO[s], 1.f));
  atomicAdd(agg + (size_t)dst[e] * 128 + d, h[(size_t)s * 128 + d] * sc);
}
__global__ __launch_bounds__(128) void k_gc1b(const float* __restrict__ agg,
    const float* __restrict__ degI, const float* __restrict__ Wt,
    const float* __restrict__ bs, float* __restrict__ h1) {
  __shared__ float vs[128];
  int n = blockIdx.x, t = threadIdx.x;
  float sc = rsqrtf(fmaxf(degI[n], 1.f));
  vs[t] = agg[(size_t)n * 128 + t] * sc;
  __syncthreads();
  float acc = bs[t];
#pragma unroll 8
  for (int d = 0; d < 128; ++d) acc = fmaf(vs[d], Wt[d * 128 + t], acc);
  h1[(size_t)n * 128 + t] = fmaxf(acc, 0.f);
}
__global__ __launch_bounds__(128) void k_gc2b(const float* __restrict__ agg,
    const float* __restrict__ degI, const float* __restrict__ Wt,
    const float* __restrict__ bs, float* __restrict__ h2) {
  __shared__ float vs[128];
  int n = blockIdx.x, t = threadIdx.x;
  float sc = rsqrtf(fmaxf(degI[n], 1.f));
  vs[t] = agg[(size_t)n * 128 + t] * sc;
  __syncthreads();
  if (t < 8) {
    float acc = bs[t];
#pragma unroll 8
    for (int d = 0; d < 128; ++d) acc = fmaf(vs[d], Wt[d * 8 + t], acc);
    h2[(size_t)n * 8 + t] = acc;   // no relu
  }
}
__global__ __launch_bounds__(128) void k_e12(const float* __restrict__ ef,
    const float* __restrict__ W1, const float* __restrict__ b1,
    const float* __restrict__ W2, const float* __restrict__ b2,
    float* __restrict__ e2) {
  __shared__ float efs[128];
  __shared__ float t1s[128];
  int t = threadIdx.x;
  for (int it = 0; it < 16; ++it) {
    int b = blockIdx.x * 16 + it;
    efs[t] = ef[(size_t)b * 128 + t];
    __syncthreads();
    float acc = b1[t];
#pragma unroll 8
    for (int d = 0; d < 128; ++d) acc = fmaf(efs[d], W1[d * 128 + t], acc);
    t1s[t] = fmaxf(acc, 0.f);
    __syncthreads();
    if (t < 8) {
      float a2 = b2[t];
#pragma unroll 8
      for (int h = 0; h < 128; ++h) a2 = fmaf(t1s[h], W2[h * 8 + t], a2);
      e2[(size_t)b * 8 + t] = fmaxf(a2, 0.f);
    }
    __syncthreads();
  }
}

// ---------- fused conv + fc1 GEMM ----------
// grid 512: bid -> i=bid&7, oh=(bid>>3)&1, jh=(bid>>4)&1, btile=bid>>5
// 32-way split-K, 2 blocks/CU (LDS 64KB, VGPR capped via launch_bounds(512,4)).
// kslice = bid&31 constant per XCD-residency group -> B-chunk L2 locality.
#define NS 64
struct Win { u16x8 a0, a1, b0, b1; uint16_t ae, be; };

__global__ __launch_bounds__(512, 4) void k_gemm(const uint16_t* __restrict__ W1s,
    const uint16_t* __restrict__ att, const float* __restrict__ conv_w,
    const float* __restrict__ conv_b, float* __restrict__ out1) {
  __shared__ __align__(16) char smem[65536];
  char* Abuf = smem;            // [2][16384]  A-tile [256m][32k] bf16, S64-swizzled
  char* Bbuf = smem + 32768;    // [2][16384]  W chunk, pre-swizzled in global

  const int tid = threadIdx.x;
  const int lane = tid & 63, ln15 = lane & 15, g = lane >> 4;
  const int wid = tid >> 6, wm = wid >> 2, wn = wid & 3;
  const int bid = blockIdx.x;
  const int i_row = bid & 7, oh = (bid >> 3) & 1, jh = (bid >> 4) & 1;
  const int btile = bid >> 5;
  const int b0 = btile * 256;
  const int am = tid >> 1, ag = tid & 1;   // A-gen: row am, k-half ag

  f32x4 acc[8][4];
#pragma unroll
  for (int mt = 0; mt < 8; ++mt)
#pragma unroll
    for (int nt = 0; nt < 4; ++nt) { f32x4 z = {0.f, 0.f, 0.f, 0.f}; acc[mt][nt] = z; }

  auto loadWin = [&](int ss) {
    int jg = jh * 2 + (ss & 1);
    int j0 = jg * 32 + ag * 16;
    const uint16_t* r0 = att + ((size_t)(b0 + am) * 9 + i_row) * ATT_ROW + j0;
    const uint16_t* r1 = r0 + ATT_ROW;
    Win w;
    w.a0 = *(const u16x8*)r0; w.a1 = *(const u16x8*)(r0 + 8); w.ae = r0[16];
    w.b0 = *(const u16x8*)r1; w.b1 = *(const u16x8*)(r1 + 8); w.be = r1[16];
    return w;
  };

  auto computeA = [&](const Win& w, int ss, char* Ab) {
    float t0[17], t1[17];
#pragma unroll
    for (int e = 0; e < 8; ++e) {
      t0[e] = bf2f((uint16_t)w.a0[e]); t0[e + 8] = bf2f((uint16_t)w.a1[e]);
      t1[e] = bf2f((uint16_t)w.b0[e]); t1[e + 8] = bf2f((uint16_t)w.b1[e]);
    }
    t0[16] = bf2f(w.ae); t1[16] = bf2f(w.be);
    int o = oh * 32 + (ss >> 1);
    float c0  = conv_b[o];
    float k00 = conv_w[o * 4 + 0], k01 = conv_w[o * 4 + 1];
    float k10 = conv_w[o * 4 + 2], k11 = conv_w[o * 4 + 3];
    uint32_t pk[8];
#pragma unroll
    for (int e2 = 0; e2 < 16; e2 += 2) {
      float v0 = fmaf(k00, t0[e2],     fmaf(k01, t0[e2 + 1], fmaf(k10, t1[e2],     fmaf(k11, t1[e2 + 1], c0))));
      float v1 = fmaf(k00, t0[e2 + 1], fmaf(k01, t0[e2 + 2], fmaf(k10, t1[e2 + 1], fmaf(k11, t1[e2 + 2], c0))));
      v0 = fmaxf(v0, 0.f); v1 = fmaxf(v1, 0.f);
      uint32_t pr;
      asm("v_cvt_pk_bf16_f32 %0, %1, %2" : "=v"(pr) : "v"(v0), "v"(v1));
      pk[e2 >> 1] = pr;
    }
    int base = am * 64 + ag * 32;
    u32x4 wv0; wv0.x = pk[0]; wv0.y = pk[1]; wv0.z = pk[2]; wv0.w = pk[3];
    u32x4 wv1; wv1.x = pk[4]; wv1.y = pk[5]; wv1.z = pk[6]; wv1.w = pk[7];
    *(u32x4*)(Ab + S64s(base))      = wv0;
    *(u32x4*)(Ab + S64s(base + 16)) = wv1;
  };

  auto stageB = [&](int ss, char* Bb) {
    int jg = jh * 2 + (ss & 1);
    int c = (oh * 32 + (ss >> 1)) * 32 + i_row * 4 + jg;
    const char* gsrc = (const char*)W1s + (size_t)c * 16384;
#pragma unroll
    for (int it = 0; it < 2; ++it) {
      char* ldsb = Bb + (size_t)(it * 512 + (tid & ~63)) * 16;   // wave-uniform base
      cp16(ldsb, gsrc + (size_t)(it * 512 + tid) * 16);
    }
  };

  auto mfmaStep = [&](const char* Ab, const char* Bb) {
    bf16x8 bfr[4];
#pragma unroll
    for (int nt = 0; nt < 4; ++nt) {
      int n = wn * 64 + nt * 16 + ln15;
      bfr[nt] = *(const bf16x8*)(Bb + S64s(n * 64 + g * 16));
    }
    bf16x8 afr[8];
#pragma unroll
    for (int mt = 0; mt < 8; ++mt) {
      int m = wm * 128 + mt * 16 + ln15;
      afr[mt] = *(const bf16x8*)(Ab + S64s(m * 64 + g * 16));
    }
#pragma unroll
    for (int mt = 0; mt < 8; ++mt)
#pragma unroll
      for (int nt = 0; nt < 4; ++nt)
        acc[mt][nt] = __builtin_amdgcn_mfma_f32_16x16x32_bf16(afr[mt], bfr[nt], acc[mt][nt], 0, 0, 0);
  };

  // prologue
  Win wA = loadWin(0);
  computeA(wA, 0, Abuf);
  stageB(0, Bbuf);
  Win wB = loadWin(1);
  __syncthreads();

#pragma unroll 1
  for (int s2 = 0; s2 < NS; s2 += 2) {
    { // even ss: consume buf0; issue loads early so latency hides under compute
      const int ss = s2;
      if (ss + 1 < NS) stageB(ss + 1, Bbuf + 16384);
      if (ss + 2 < NS) wA = loadWin(ss + 2);
      if (ss + 1 < NS) computeA(wB, ss + 1, Abuf + 16384);
      mfmaStep(Abuf, Bbuf);
      __syncthreads();
    }
    { // odd ss: consume buf1
      const int ss = s2 + 1;
      if (ss + 1 < NS) stageB(ss + 1, Bbuf);
      if (ss + 2 < NS) wB = loadWin(ss + 2);
      if (ss + 1 < NS) computeA(wA, ss + 1, Abuf);
      mfmaStep(Abuf + 16384, Bbuf + 16384);
      __syncthreads();
    }
  }

  // epilogue: split-K accumulate (32 partial adds per out element)
  const int rbase = b0 + wm * 128 + (lane >> 4) * 4;
  const int cbase = wn * 64 + ln15;
#pragma unroll
  for (int mt = 0; mt < 8; ++mt)
#pragma unroll
    for (int nt = 0; nt < 4; ++nt)
#pragma unroll
      for (int r = 0; r < 4; ++r)
        atomicAdd(out1 + (size_t)(rbase + mt * 16 + r) * 256 + cbase + nt * 16,
                  acc[mt][nt][r]);
}

// ---------- final: bias+relu, fc2, node_feats, fc3 ----------
__global__ __launch_bounds__(512) void k_fin(const float* __restrict__ out1,
    const float* __restrict__ fc1_b, const float* __restrict__ fc2_W,
    const float* __restrict__ fc2_b, const float* __restrict__ fc3_W,
    const float* __restrict__ fc3_b, const int* __restrict__ src,
    const int* __restrict__ dst, const float* __restrict__ h2,
    const float* __restrict__ e2, float* __restrict__ outp) {
  int lane = threadIdx.x & 63, w = threadIdx.x >> 6;
  int b  = blockIdx.x * 8 + w;
  int bu = __builtin_amdgcn_readfirstlane(b);
  f32x4 o4 = ((const f32x4*)(out1 + (size_t)bu * 256))[lane];
  f32x4 bi = ((const f32x4*)fc1_b)[lane];
  float v[4];
#pragma unroll
  for (int r = 0; r < 4; ++r) v[r] = fmaxf(o4[r] + bi[r], 0.f);
  float a24[24];
#pragma unroll
  for (int q = 0; q < 24; ++q) a24[q] = 0.f;
#pragma unroll
  for (int r = 0; r < 4; ++r) {
    const float* wr = fc2_W + (size_t)(lane * 4 + r) * 24;
#pragma unroll
    for (int q = 0; q < 24; ++q) a24[q] = fmaf(v[r], wr[q], a24[q]);
  }
#pragma unroll
  for (int q = 0; q < 24; ++q) {
    float t = a24[q];
    t += __shfl_xor(t, 1);  t += __shfl_xor(t, 2);  t += __shfl_xor(t, 4);
    t += __shfl_xor(t, 8);  t += __shfl_xor(t, 16); t += __shfl_xor(t, 32);
    a24[q] = fmaxf(t + fc2_b[q], 0.f);
  }
  int s = src[bu], d2 = dst[bu];
  float nf[24];
#pragma unroll
  for (int q = 0; q < 8; ++q) {
    float hs = h2[(size_t)s * 8 + q];
    float hd = h2[(size_t)d2 * 8 + q];
    nf[q] = hs; nf[8 + q] = hd; nf[16 + q] = hs + hd + e2[(size_t)bu * 8 + q];
  }
  if (lane == 0) {
#pragma unroll
    for (int c = 0; c < 2; ++c) {
      float r = fc3_b[c];
#pragma unroll
      for (int q = 0; q < 24; ++q) r = fmaf(a24[q], fc3_W[q * 2 + c], r);
#pragma unroll
      for (int q = 0; q < 24; ++q) r = fmaf(nf[q], fc3_W[(24 + q) * 2 + c], r);
      outp[(size_t)bu * 2 + c] = r;
    }
  }
}

// ---------- launch ----------
extern "C" void kernel_launch(void* const* d_in, const int* in_sizes, int n_in,
                              void* d_out, int out_size, void* d_ws, size_t ws_size,
                              hipStream_t stream) {
  const float* X         = (const float*)d_in[0];
  const int*   src       = (const int*)d_in[1];
  const int*   dst       = (const int*)d_in[2];
  const float* node_feat = (const float*)d_in[3];
  const float* edge_feat = (const float*)d_in[4];
  const float* attn_W    = (const float*)d_in[5];
  const float* attn_U    = (const float*)d_in[6];
  const float* attn_V    = (const float*)d_in[7];
  const float* conv_w    = (const float*)d_in[8];
  const float* conv_b    = (const float*)d_in[9];
  const float* gc1_W     = (const float*)d_in[10];
  const float* gc1_b     = (const float*)d_in[11];
  const float* gc2_W     = (const float*)d_in[12];
  const float* gc2_b     = (const float*)d_in[13];
  const float* lin1_W    = (const float*)d_in[14];
  const float* lin1_b    = (const float*)d_in[15];
  const float* lin2_W    = (const float*)d_in[16];
  const float* lin2_b    = (const float*)d_in[17];
  const float* fc1_W     = (const float*)d_in[18];
  const float* fc1_b     = (const float*)d_in[19];
  const float* fc2_W     = (const float*)d_in[20];
  const float* fc2_b     = (const float*)d_in[21];
  const float* fc3_W     = (const float*)d_in[22];
  const float* fc3_b     = (const float*)d_in[23];

  char* ws = (char*)d_ws;
  float*    out1 = (float*)(ws + 0);               // 4096*256*4      = 4,194,304
  float*    agg1 = (float*)(ws + 4194304);         // 2048*128*4      = 1,048,576
  float*    agg2 = (float*)(ws + 5242880);         // 2048*128*4      = 1,048,576
  float*    degO = (float*)(ws + 6291456);         // 2048*4
  float*    degI = (float*)(ws + 6299648);         // 2048*4
  uint16_t* W1s  = (uint16_t*)(ws + 6307840);      // 65536*256*2     = 33,554,432
  uint16_t* att  = (uint16_t*)(ws + 39862272);     // 4096*9*136*2    = 10,027,008
  float*    h1   = (float*)(ws + 49889280);        // 2048*128*4
  float*    h2   = (float*)(ws + 50937856);        // 2048*8*4
  float*    e2   = (float*)(ws + 51003392);        // 4096*8*4

  hipMemsetAsync(d_ws, 0, 6307840, stream);        // out1, agg1, agg2, degs

  k_prep<<<dim3(2048), dim3(256), 0, stream>>>(fc1_W, W1s);
  k_att <<<dim3(256),  dim3(512), 0, stream>>>(X, attn_W, attn_U, attn_V, att);
  k_deg <<<dim3(16),   dim3(256), 0, stream>>>(src, dst, degO, degI);
  k_gca <<<dim3(2048), dim3(256), 0, stream>>>(node_feat, src, dst, degO, agg1);
  k_gc1b<<<dim3(2048), dim3(128), 0, stream>>>(agg1, degI, gc1_W, gc1_b, h1);
  k_gca <<<dim3(2048), dim3(256), 0, stream>>>(h1, src, dst, degO, agg2);
  k_gc2b<<<dim3(2048), dim3(128), 0, stream>>>(agg2, degI, gc2_W, gc2_b, h2);
  k_e12 <<<dim3(256),  dim3(128), 0, stream>>>(edge_feat, lin1_W, lin1_b, lin2_W, lin2_b, e2);
  k_gemm<<<dim3(512),  dim3(512), 0, stream>>>(W1s, att, conv_w, conv_b, out1);
  k_fin <<<dim3(512),  dim3(512), 0, stream>>>(out1, fc1_b, fc2_W, fc2_b, fc3_W, fc3_b,
                                               src, dst, h2, e2, (float*)d_out);
}

// Round 4
// 558.932 us; speedup vs baseline: 3.1295x; 3.1295x over previous
//
#include <hip/hip_runtime.h>
#include <stdint.h>
#include <stddef.h>

typedef float    f32x4  __attribute__((ext_vector_type(4)));
typedef short    bf16x8 __attribute__((ext_vector_type(8)));
typedef uint16_t u16x8  __attribute__((ext_vector_type(8)));
typedef uint32_t u32x4  __attribute__((ext_vector_type(4)));

#define ATT_ROW 136   // 128 data + 8 zero pad (=> 272B rows, 16B aligned)

// ---------- helpers ----------
__device__ __forceinline__ uint16_t f2bf(float x) {
  union { float f; uint32_t u; } c; c.f = x;
  return (uint16_t)((c.u + 0x7FFFu + ((c.u >> 16) & 1u)) >> 16);  // RNE
}
__device__ __forceinline__ float bf2f(uint16_t h) {
  union { uint32_t u; float f; } c; c.u = ((uint32_t)h) << 16;
  return c.f;
}
// XOR swizzle for 64B-row LDS tiles: byte a -> a ^ ((row-bits)<<4). Bijective;
// used consistently on write+read, with explicit inverse in k_prep.
__device__ __forceinline__ int S64s(int a) { return a ^ (((a >> 6) & 7) << 4); }

__device__ __forceinline__ void cp16(void* lds, const void* g) {
  __builtin_amdgcn_global_load_lds((const __attribute__((address_space(1))) void*)g,
                                   (__attribute__((address_space(3))) void*)lds, 16, 0, 0);
}
__device__ __forceinline__ float fast_tanh(float t) {
  float r = __expf(-2.f * t);
  return 1.f - 2.f * r / (1.f + r);
}

// ---------- prep: fc1_W (fp32 [65536][256]) -> bf16 chunked column-major, swizzled ----------
__global__ __launch_bounds__(256) void k_prep(const float* __restrict__ W1,
                                              uint16_t* __restrict__ W1s) {
  __shared__ float st[32 * 256];
  const int c = blockIdx.x, tid = threadIdx.x;
  const float* src = W1 + (size_t)c * 32 * 256;
#pragma unroll
  for (int it = 0; it < 8; ++it) {
    int u = it * 256 + tid;
    ((f32x4*)st)[u] = ((const f32x4*)src)[u];
  }
  __syncthreads();
  uint16_t* dstc = W1s + (size_t)c * 8192;
#pragma unroll
  for (int q = 0; q < 4; ++q) {
    int p  = q * 256 + tid;       // 16B unit 0..1023
    int Np = p >> 2, Gp = p & 3;
    int n  = Np ^ ((Np >> 2) & 1);   // invert S64
    int g  = Gp ^ (n & 3);
    uint32_t w[4];
#pragma unroll
    for (int e2 = 0; e2 < 4; ++e2) {
      uint16_t lo = f2bf(st[(g * 8 + 2 * e2) * 256 + n]);
      uint16_t hi = f2bf(st[(g * 8 + 2 * e2 + 1) * 256 + n]);
      w[e2] = (uint32_t)lo | ((uint32_t)hi << 16);
    }
    u32x4 v; v.x = w[0]; v.y = w[1]; v.z = w[2]; v.w = w[3];
    *(u32x4*)(dstc + (size_t)p * 8) = v;
  }
}

// ---------- attention ----------
__global__ __launch_bounds__(512) void k_att(const float* __restrict__ X,
    const float* __restrict__ aW, const float* __restrict__ aU,
    const float* __restrict__ aV, uint16_t* __restrict__ att) {
  __shared__ float sa[8][8][66];
  __shared__ float su[8][8][66];
  __shared__ float sal[8][64];
  __shared__ float sv[64];
  const int tid = threadIdx.x, lane = tid & 63, w = tid >> 6;
  if (tid < 64) sv[tid] = aV[tid];
  __syncthreads();
  for (int rep = 0; rep < 2; ++rep) {
    int b  = blockIdx.x * 16 + w * 2 + rep;
    int bu = __builtin_amdgcn_readfirstlane(b);
    const float* xb = X + (size_t)bu * 512;
    float xi[8];
#pragma unroll
    for (int i = 0; i < 8; ++i) xi[i] = xb[i * 64 + lane];
    float a[8], u[8];
#pragma unroll
    for (int i = 0; i < 8; ++i) { a[i] = 0.f; u[i] = 0.f; }
#pragma unroll
    for (int f = 0; f < 64; ++f) {
      float wf = aW[f * 64 + lane];
      float uf = aU[f * 64 + lane];
#pragma unroll
      for (int i = 0; i < 8; ++i) {
        float xs = xb[i * 64 + f];      // wave-uniform -> s_load
        a[i] = fmaf(xs, wf, a[i]);
        u[i] = fmaf(xs, uf, u[i]);
      }
    }
#pragma unroll
    for (int i = 0; i < 8; ++i) { sa[w][i][lane] = a[i]; su[w][i][lane] = u[i]; }
    __syncthreads();
    int i2 = lane >> 3, j2 = lane & 7;
    float ev = 0.f;
#pragma unroll
    for (int h = 0; h < 64; ++h)
      ev = fmaf(fast_tanh(sa[w][i2][h] + su[w][j2][h]), sv[h], ev);
    float m = ev;
    m = fmaxf(m, __shfl_xor(m, 1));
    m = fmaxf(m, __shfl_xor(m, 2));
    m = fmaxf(m, __shfl_xor(m, 4));
    float p = __expf(ev - m);
    float s = p;
    s += __shfl_xor(s, 1); s += __shfl_xor(s, 2); s += __shfl_xor(s, 4);
    sal[w][lane] = p / s;
    __syncthreads();
#pragma unroll
    for (int i = 0; i < 8; ++i) {
      float c = 0.f;
#pragma unroll
      for (int j = 0; j < 8; ++j) c = fmaf(sal[w][i * 8 + j], xi[j], c);
      c = fmaf(-sal[w][i * 8 + i], xi[i], c);
      size_t ro = ((size_t)b * 9 + i) * ATT_ROW;
      att[ro + lane]      = f2bf(xi[i]);
      att[ro + 64 + lane] = f2bf(c);
      if (lane < 8) att[ro + 128 + lane] = 0;
    }
    {
      size_t ro = ((size_t)b * 9 + 8) * ATT_ROW;
      att[ro + lane] = 0; att[ro + 64 + lane] = 0;
      if (lane < 8) att[ro + 128 + lane] = 0;
    }
    __syncthreads();
  }
}

// ---------- graph path ----------
__global__ void k_deg(const int* __restrict__ src, const int* __restrict__ dst,
                      float* degO, float* degI) {
  int t = blockIdx.x * 256 + threadIdx.x;
  if (t < 4096) {
    atomicAdd(degO + src[t], 1.f);
    atomicAdd(degI + dst[t], 1.f);
  }
}
__global__ __launch_bounds__(256) void k_gca(const float* __restrict__ h,
    const int* __restrict__ src, const int* __restrict__ dst,
    const float* __restrict__ degO, float* __restrict__ agg) {
  int t = blockIdx.x * 256 + threadIdx.x;   // 4096*128
  int e = t >> 7, d = t & 127;
  int s = src[e];
  float sc = rsqrtf(fmaxf(degO[s], 1.f));
  atomicAdd(agg + (size_t)dst[e] * 128 + d, h[(size_t)s * 128 + d] * sc);
}
__global__ __launch_bounds__(128) void k_gc1b(const float* __restrict__ agg,
    const float* __restrict__ degI, const float* __restrict__ Wt,
    const float* __restrict__ bs, float* __restrict__ h1) {
  __shared__ float vs[128];
  int n = blockIdx.x, t = threadIdx.x;
  float sc = rsqrtf(fmaxf(degI[n], 1.f));
  vs[t] = agg[(size_t)n * 128 + t] * sc;
  __syncthreads();
  float acc = bs[t];
#pragma unroll 8
  for (int d = 0; d < 128; ++d) acc = fmaf(vs[d], Wt[d * 128 + t], acc);
  h1[(size_t)n * 128 + t] = fmaxf(acc, 0.f);
}
__global__ __launch_bounds__(128) void k_gc2b(const float* __restrict__ agg,
    const float* __restrict__ degI, const float* __restrict__ Wt,
    const float* __restrict__ bs, float* __restrict__ h2) {
  __shared__ float vs[128];
  int n = blockIdx.x, t = threadIdx.x;
  float sc = rsqrtf(fmaxf(degI[n], 1.f));
  vs[t] = agg[(size_t)n * 128 + t] * sc;
  __syncthreads();
  if (t < 8) {
    float acc = bs[t];
#pragma unroll 8
    for (int d = 0; d < 128; ++d) acc = fmaf(vs[d], Wt[d * 8 + t], acc);
    h2[(size_t)n * 8 + t] = acc;   // no relu
  }
}
__global__ __launch_bounds__(128) void k_e12(const float* __restrict__ ef,
    const float* __restrict__ W1, const float* __restrict__ b1,
    const float* __restrict__ W2, const float* __restrict__ b2,
    float* __restrict__ e2) {
  __shared__ float efs[128];
  __shared__ float t1s[128];
  int t = threadIdx.x;
  for (int it = 0; it < 16; ++it) {
    int b = blockIdx.x * 16 + it;
    efs[t] = ef[(size_t)b * 128 + t];
    __syncthreads();
    float acc = b1[t];
#pragma unroll 8
    for (int d = 0; d < 128; ++d) acc = fmaf(efs[d], W1[d * 128 + t], acc);
    t1s[t] = fmaxf(acc, 0.f);
    __syncthreads();
    if (t < 8) {
      float a2 = b2[t];
#pragma unroll 8
      for (int h = 0; h < 128; ++h) a2 = fmaf(t1s[h], W2[h * 8 + t], a2);
      e2[(size_t)b * 8 + t] = fmaxf(a2, 0.f);
    }
    __syncthreads();
  }
}

// ---------- fused conv + fc1 GEMM ----------
// BM=128, BN=256, BK=32. grid 1024: i=bid&7, oh=(bid>>3)&1, jh=(bid>>4)&1,
// btile=bid>>5 (32 tiles of 128 rows). 32-way split-K.
// 8 waves as 2M x 4N -> wave tile 64x64 -> acc = 64 AGPR; total regs ~124 <= 128
// so __launch_bounds__(512,4) gives 2 blocks/CU WITHOUT spilling (R3 lesson:
// 256-row tile had acc=128 AGPR -> forced spill -> 7GB scratch traffic).
#define NS 64
struct Win { u16x8 a0, b0; uint16_t ae, be; };

__global__ __launch_bounds__(512, 4) void k_gemm(const uint16_t* __restrict__ W1s,
    const uint16_t* __restrict__ att, const float* __restrict__ conv_w,
    const float* __restrict__ conv_b, float* __restrict__ out1) {
  __shared__ __align__(16) char smem[49152];
  char* Abuf = smem;            // [2][8192]   A-tile [128m][32k] bf16, S64-swizzled
  char* Bbuf = smem + 16384;    // [2][16384]  W chunk [256n][32k], pre-swizzled global

  const int tid = threadIdx.x;
  const int lane = tid & 63, ln15 = lane & 15, g = lane >> 4;
  const int wid = tid >> 6, wm = wid >> 2, wn = wid & 3;
  const int bid = blockIdx.x;
  const int i_row = bid & 7, oh = (bid >> 3) & 1, jh = (bid >> 4) & 1;
  const int btile = bid >> 5;
  const int b0 = btile * 128;
  const int am = tid >> 2, ag = tid & 3;   // A-gen: row am (0..127), k-octet ag (0..3)

  f32x4 acc[4][4];
#pragma unroll
  for (int mt = 0; mt < 4; ++mt)
#pragma unroll
    for (int nt = 0; nt < 4; ++nt) { f32x4 z = {0.f, 0.f, 0.f, 0.f}; acc[mt][nt] = z; }

  auto loadWin = [&](int ss) {
    int jg = jh * 2 + (ss & 1);
    int j0 = jg * 32 + ag * 8;
    const uint16_t* r0 = att + ((size_t)(b0 + am) * 9 + i_row) * ATT_ROW + j0;
    const uint16_t* r1 = r0 + ATT_ROW;
    Win w;
    w.a0 = *(const u16x8*)r0; w.ae = r0[8];
    w.b0 = *(const u16x8*)r1; w.be = r1[8];
    return w;
  };

  auto computeA = [&](const Win& w, int ss, char* Ab) {
    float t0[9], t1[9];
#pragma unroll
    for (int e = 0; e < 8; ++e) {
      t0[e] = bf2f((uint16_t)w.a0[e]);
      t1[e] = bf2f((uint16_t)w.b0[e]);
    }
    t0[8] = bf2f(w.ae); t1[8] = bf2f(w.be);
    int o = oh * 32 + (ss >> 1);
    float c0  = conv_b[o];
    float k00 = conv_w[o * 4 + 0], k01 = conv_w[o * 4 + 1];
    float k10 = conv_w[o * 4 + 2], k11 = conv_w[o * 4 + 3];
    uint32_t pk[4];
#pragma unroll
    for (int e2 = 0; e2 < 8; e2 += 2) {
      float v0 = fmaf(k00, t0[e2],     fmaf(k01, t0[e2 + 1], fmaf(k10, t1[e2],     fmaf(k11, t1[e2 + 1], c0))));
      float v1 = fmaf(k00, t0[e2 + 1], fmaf(k01, t0[e2 + 2], fmaf(k10, t1[e2 + 1], fmaf(k11, t1[e2 + 2], c0))));
      v0 = fmaxf(v0, 0.f); v1 = fmaxf(v1, 0.f);
      uint32_t pr;
      asm("v_cvt_pk_bf16_f32 %0, %1, %2" : "=v"(pr) : "v"(v0), "v"(v1));
      pk[e2 >> 1] = pr;
    }
    u32x4 wv; wv.x = pk[0]; wv.y = pk[1]; wv.z = pk[2]; wv.w = pk[3];
    *(u32x4*)(Ab + S64s(am * 64 + ag * 16)) = wv;
  };

  auto stageB = [&](int ss, char* Bb) {
    int jg = jh * 2 + (ss & 1);
    int c = (oh * 32 + (ss >> 1)) * 32 + i_row * 4 + jg;
    const char* gsrc = (const char*)W1s + (size_t)c * 16384;
#pragma unroll
    for (int it = 0; it < 2; ++it) {
      char* ldsb = Bb + (size_t)(it * 512 + (tid & ~63)) * 16;   // wave-uniform base
      cp16(ldsb, gsrc + (size_t)(it * 512 + tid) * 16);
    }
  };

  auto mfmaStep = [&](const char* Ab, const char* Bb) {
    bf16x8 bfr[4];
#pragma unroll
    for (int nt = 0; nt < 4; ++nt) {
      int n = wn * 64 + nt * 16 + ln15;
      bfr[nt] = *(const bf16x8*)(Bb + S64s(n * 64 + g * 16));
    }
    bf16x8 afr[4];
#pragma unroll
    for (int mt = 0; mt < 4; ++mt) {
      int m = wm * 64 + mt * 16 + ln15;
      afr[mt] = *(const bf16x8*)(Ab + S64s(m * 64 + g * 16));
    }
#pragma unroll
    for (int mt = 0; mt < 4; ++mt)
#pragma unroll
      for (int nt = 0; nt < 4; ++nt)
        acc[mt][nt] = __builtin_amdgcn_mfma_f32_16x16x32_bf16(afr[mt], bfr[nt], acc[mt][nt], 0, 0, 0);
  };

  // prologue
  Win wA = loadWin(0);
  computeA(wA, 0, Abuf);
  stageB(0, Bbuf);
  Win wB = loadWin(1);
  __syncthreads();

#pragma unroll 1
  for (int s2 = 0; s2 < NS; s2 += 2) {
    { // even ss: consume buf0; issue loads early so latency hides under compute
      const int ss = s2;
      if (ss + 1 < NS) stageB(ss + 1, Bbuf + 16384);
      if (ss + 2 < NS) wA = loadWin(ss + 2);
      if (ss + 1 < NS) computeA(wB, ss + 1, Abuf + 8192);
      mfmaStep(Abuf, Bbuf);
      __syncthreads();
    }
    { // odd ss: consume buf1
      const int ss = s2 + 1;
      if (ss + 1 < NS) stageB(ss + 1, Bbuf);
      if (ss + 2 < NS) wB = loadWin(ss + 2);
      if (ss + 1 < NS) computeA(wA, ss + 1, Abuf);
      mfmaStep(Abuf + 8192, Bbuf + 16384);
      __syncthreads();
    }
  }

  // epilogue: split-K accumulate (32 partial adds per out element)
  const int rbase = b0 + wm * 64 + (lane >> 4) * 4;
  const int cbase = wn * 64 + ln15;
#pragma unroll
  for (int mt = 0; mt < 4; ++mt)
#pragma unroll
    for (int nt = 0; nt < 4; ++nt)
#pragma unroll
      for (int r = 0; r < 4; ++r)
        atomicAdd(out1 + (size_t)(rbase + mt * 16 + r) * 256 + cbase + nt * 16,
                  acc[mt][nt][r]);
}

// ---------- final: bias+relu, fc2, node_feats, fc3 ----------
__global__ __launch_bounds__(512) void k_fin(const float* __restrict__ out1,
    const float* __restrict__ fc1_b, const float* __restrict__ fc2_W,
    const float* __restrict__ fc2_b, const float* __restrict__ fc3_W,
    const float* __restrict__ fc3_b, const int* __restrict__ src,
    const int* __restrict__ dst, const float* __restrict__ h2,
    const float* __restrict__ e2, float* __restrict__ outp) {
  int lane = threadIdx.x & 63, w = threadIdx.x >> 6;
  int b  = blockIdx.x * 8 + w;
  int bu = __builtin_amdgcn_readfirstlane(b);
  f32x4 o4 = ((const f32x4*)(out1 + (size_t)bu * 256))[lane];
  f32x4 bi = ((const f32x4*)fc1_b)[lane];
  float v[4];
#pragma unroll
  for (int r = 0; r < 4; ++r) v[r] = fmaxf(o4[r] + bi[r], 0.f);
  float a24[24];
#pragma unroll
  for (int q = 0; q < 24; ++q) a24[q] = 0.f;
#pragma unroll
  for (int r = 0; r < 4; ++r) {
    const float* wr = fc2_W + (size_t)(lane * 4 + r) * 24;
#pragma unroll
    for (int q = 0; q < 24; ++q) a24[q] = fmaf(v[r], wr[q], a24[q]);
  }
#pragma unroll
  for (int q = 0; q < 24; ++q) {
    float t = a24[q];
    t += __shfl_xor(t, 1);  t += __shfl_xor(t, 2);  t += __shfl_xor(t, 4);
    t += __shfl_xor(t, 8);  t += __shfl_xor(t, 16); t += __shfl_xor(t, 32);
    a24[q] = fmaxf(t + fc2_b[q], 0.f);
  }
  int s = src[bu], d2 = dst[bu];
  float nf[24];
#pragma unroll
  for (int q = 0; q < 8; ++q) {
    float hs = h2[(size_t)s * 8 + q];
    float hd = h2[(size_t)d2 * 8 + q];
    nf[q] = hs; nf[8 + q] = hd; nf[16 + q] = hs + hd + e2[(size_t)bu * 8 + q];
  }
  if (lane == 0) {
#pragma unroll
    for (int c = 0; c < 2; ++c) {
      float r = fc3_b[c];
#pragma unroll
      for (int q = 0; q < 24; ++q) r = fmaf(a24[q], fc3_W[q * 2 + c], r);
#pragma unroll
      for (int q = 0; q < 24; ++q) r = fmaf(nf[q], fc3_W[(24 + q) * 2 + c], r);
      outp[(size_t)bu * 2 + c] = r;
    }
  }
}

// ---------- launch ----------
extern "C" void kernel_launch(void* const* d_in, const int* in_sizes, int n_in,
                              void* d_out, int out_size, void* d_ws, size_t ws_size,
                              hipStream_t stream) {
  const float* X         = (const float*)d_in[0];
  const int*   src       = (const int*)d_in[1];
  const int*   dst       = (const int*)d_in[2];
  const float* node_feat = (const float*)d_in[3];
  const float* edge_feat = (const float*)d_in[4];
  const float* attn_W    = (const float*)d_in[5];
  const float* attn_U    = (const float*)d_in[6];
  const float* attn_V    = (const float*)d_in[7];
  const float* conv_w    = (const float*)d_in[8];
  const float* conv_b    = (const float*)d_in[9];
  const float* gc1_W     = (const float*)d_in[10];
  const float* gc1_b     = (const float*)d_in[11];
  const float* gc2_W     = (const float*)d_in[12];
  const float* gc2_b     = (const float*)d_in[13];
  const float* lin1_W    = (const float*)d_in[14];
  const float* lin1_b    = (const float*)d_in[15];
  const float* lin2_W    = (const float*)d_in[16];
  const float* lin2_b    = (const float*)d_in[17];
  const float* fc1_W     = (const float*)d_in[18];
  const float* fc1_b     = (const float*)d_in[19];
  const float* fc2_W     = (const float*)d_in[20];
  const float* fc2_b     = (const float*)d_in[21];
  const float* fc3_W     = (const float*)d_in[22];
  const float* fc3_b     = (const float*)d_in[23];

  char* ws = (char*)d_ws;
  float*    out1 = (float*)(ws + 0);               // 4096*256*4      = 4,194,304
  float*    agg1 = (float*)(ws + 4194304);         // 2048*128*4      = 1,048,576
  float*    agg2 = (float*)(ws + 5242880);         // 2048*128*4      = 1,048,576
  float*    degO = (float*)(ws + 6291456);         // 2048*4
  float*    degI = (float*)(ws + 6299648);         // 2048*4
  uint16_t* W1s  = (uint16_t*)(ws + 6307840);      // 65536*256*2     = 33,554,432
  uint16_t* att  = (uint16_t*)(ws + 39862272);     // 4096*9*136*2    = 10,027,008
  float*    h1   = (float*)(ws + 49889280);        // 2048*128*4
  float*    h2   = (float*)(ws + 50937856);        // 2048*8*4
  float*    e2   = (float*)(ws + 51003392);        // 4096*8*4

  hipMemsetAsync(d_ws, 0, 6307840, stream);        // out1, agg1, agg2, degs

  k_prep<<<dim3(2048), dim3(256), 0, stream>>>(fc1_W, W1s);
  k_att <<<dim3(256),  dim3(512), 0, stream>>>(X, attn_W, attn_U, attn_V, att);
  k_deg <<<dim3(16),   dim3(256), 0, stream>>>(src, dst, degO, degI);
  k_gca <<<dim3(2048), dim3(256), 0, stream>>>(node_feat, src, dst, degO, agg1);
  k_gc1b<<<dim3(2048), dim3(128), 0, stream>>>(agg1, degI, gc1_W, gc1_b, h1);
  k_gca <<<dim3(2048), dim3(256), 0, stream>>>(h1, src, dst, degO, agg2);
  k_gc2b<<<dim3(2048), dim3(128), 0, stream>>>(agg2, degI, gc2_W, gc2_b, h2);
  k_e12 <<<dim3(256),  dim3(128), 0, stream>>>(edge_feat, lin1_W, lin1_b, lin2_W, lin2_b, e2);
  k_gemm<<<dim3(1024), dim3(512), 0, stream>>>(W1s, att, conv_w, conv_b, out1);
  k_fin <<<dim3(512),  dim3(512), 0, stream>>>(out1, fc1_b, fc2_W, fc2_b, fc3_W, fc3_b,
                                               src, dst, h2, e2, (float*)d_out);
}

// Round 5
// 554.065 us; speedup vs baseline: 3.1570x; 1.0088x over previous
//
#include <hip/hip_runtime.h>
#include <stdint.h>
#include <stddef.h>

typedef float    f32x4  __attribute__((ext_vector_type(4)));
typedef short    bf16x8 __attribute__((ext_vector_type(8)));
typedef uint16_t u16x8  __attribute__((ext_vector_type(8)));
typedef uint32_t u32x4  __attribute__((ext_vector_type(4)));

#define ATT_ROW 136   // 128 data + 8 zero pad (=> 272B rows, 16B aligned)

// ---------- helpers ----------
__device__ __forceinline__ uint16_t f2bf(float x) {
  union { float f; uint32_t u; } c; c.f = x;
  return (uint16_t)((c.u + 0x7FFFu + ((c.u >> 16) & 1u)) >> 16);  // RNE
}
__device__ __forceinline__ float bf2f(uint16_t h) {
  union { uint32_t u; float f; } c; c.u = ((uint32_t)h) << 16;
  return c.f;
}
// XOR swizzle for 64B-row LDS tiles: byte a -> a ^ ((row-bits)<<4). Bijective;
// used consistently on write+read, with explicit inverse in k_prep.
__device__ __forceinline__ int S64s(int a) { return a ^ (((a >> 6) & 7) << 4); }

__device__ __forceinline__ void cp16(void* lds, const void* g) {
  __builtin_amdgcn_global_load_lds((const __attribute__((address_space(1))) void*)g,
                                   (__attribute__((address_space(3))) void*)lds, 16, 0, 0);
}
__device__ __forceinline__ float fast_tanh(float t) {
  float r = __expf(-2.f * t);
  return 1.f - 2.f * r / (1.f + r);
}

// ---------- prep: fc1_W (fp32 [65536][256]) -> bf16 chunked column-major, swizzled ----------
__global__ __launch_bounds__(256) void k_prep(const float* __restrict__ W1,
                                              uint16_t* __restrict__ W1s) {
  __shared__ float st[32 * 256];
  const int c = blockIdx.x, tid = threadIdx.x;
  const float* src = W1 + (size_t)c * 32 * 256;
#pragma unroll
  for (int it = 0; it < 8; ++it) {
    int u = it * 256 + tid;
    ((f32x4*)st)[u] = ((const f32x4*)src)[u];
  }
  __syncthreads();
  uint16_t* dstc = W1s + (size_t)c * 8192;
#pragma unroll
  for (int q = 0; q < 4; ++q) {
    int p  = q * 256 + tid;       // 16B unit 0..1023
    int Np = p >> 2, Gp = p & 3;
    int n  = Np ^ ((Np >> 2) & 1);   // invert S64
    int g  = Gp ^ (n & 3);
    uint32_t w[4];
#pragma unroll
    for (int e2 = 0; e2 < 4; ++e2) {
      uint16_t lo = f2bf(st[(g * 8 + 2 * e2) * 256 + n]);
      uint16_t hi = f2bf(st[(g * 8 + 2 * e2 + 1) * 256 + n]);
      w[e2] = (uint32_t)lo | ((uint32_t)hi << 16);
    }
    u32x4 v; v.x = w[0]; v.y = w[1]; v.z = w[2]; v.w = w[3];
    *(u32x4*)(dstc + (size_t)p * 8) = v;
  }
}

// ---------- attention ----------
__global__ __launch_bounds__(512) void k_att(const float* __restrict__ X,
    const float* __restrict__ aW, const float* __restrict__ aU,
    const float* __restrict__ aV, uint16_t* __restrict__ att) {
  __shared__ float sa[8][8][66];
  __shared__ float su[8][8][66];
  __shared__ float sal[8][64];
  __shared__ float sv[64];
  const int tid = threadIdx.x, lane = tid & 63, w = tid >> 6;
  if (tid < 64) sv[tid] = aV[tid];
  __syncthreads();
  for (int rep = 0; rep < 2; ++rep) {
    int b  = blockIdx.x * 16 + w * 2 + rep;
    int bu = __builtin_amdgcn_readfirstlane(b);
    const float* xb = X + (size_t)bu * 512;
    float xi[8];
#pragma unroll
    for (int i = 0; i < 8; ++i) xi[i] = xb[i * 64 + lane];
    float a[8], u[8];
#pragma unroll
    for (int i = 0; i < 8; ++i) { a[i] = 0.f; u[i] = 0.f; }
#pragma unroll
    for (int f = 0; f < 64; ++f) {
      float wf = aW[f * 64 + lane];
      float uf = aU[f * 64 + lane];
#pragma unroll
      for (int i = 0; i < 8; ++i) {
        float xs = xb[i * 64 + f];      // wave-uniform -> s_load
        a[i] = fmaf(xs, wf, a[i]);
        u[i] = fmaf(xs, uf, u[i]);
      }
    }
#pragma unroll
    for (int i = 0; i < 8; ++i) { sa[w][i][lane] = a[i]; su[w][i][lane] = u[i]; }
    __syncthreads();
    int i2 = lane >> 3, j2 = lane & 7;
    float ev = 0.f;
#pragma unroll
    for (int h = 0; h < 64; ++h)
      ev = fmaf(fast_tanh(sa[w][i2][h] + su[w][j2][h]), sv[h], ev);
    float m = ev;
    m = fmaxf(m, __shfl_xor(m, 1));
    m = fmaxf(m, __shfl_xor(m, 2));
    m = fmaxf(m, __shfl_xor(m, 4));
    float p = __expf(ev - m);
    float s = p;
    s += __shfl_xor(s, 1); s += __shfl_xor(s, 2); s += __shfl_xor(s, 4);
    sal[w][lane] = p / s;
    __syncthreads();
#pragma unroll
    for (int i = 0; i < 8; ++i) {
      float c = 0.f;
#pragma unroll
      for (int j = 0; j < 8; ++j) c = fmaf(sal[w][i * 8 + j], xi[j], c);
      c = fmaf(-sal[w][i * 8 + i], xi[i], c);
      size_t ro = ((size_t)b * 9 + i) * ATT_ROW;
      att[ro + lane]      = f2bf(xi[i]);
      att[ro + 64 + lane] = f2bf(c);
      if (lane < 8) att[ro + 128 + lane] = 0;
    }
    {
      size_t ro = ((size_t)b * 9 + 8) * ATT_ROW;
      att[ro + lane] = 0; att[ro + 64 + lane] = 0;
      if (lane < 8) att[ro + 128 + lane] = 0;
    }
    __syncthreads();
  }
}

// ---------- graph path ----------
__global__ void k_deg(const int* __restrict__ src, const int* __restrict__ dst,
                      float* degO, float* degI) {
  int t = blockIdx.x * 256 + threadIdx.x;
  if (t < 4096) {
    atomicAdd(degO + src[t], 1.f);
    atomicAdd(degI + dst[t], 1.f);
  }
}
__global__ __launch_bounds__(256) void k_gca(const float* __restrict__ h,
    const int* __restrict__ src, const int* __restrict__ dst,
    const float* __restrict__ degO, float* __restrict__ agg) {
  int t = blockIdx.x * 256 + threadIdx.x;   // 4096*128
  int e = t >> 7, d = t & 127;
  int s = src[e];
  float sc = rsqrtf(fmaxf(degO[s], 1.f));
  atomicAdd(agg + (size_t)dst[e] * 128 + d, h[(size_t)s * 128 + d] * sc);
}
__global__ __launch_bounds__(128) void k_gc1b(const float* __restrict__ agg,
    const float* __restrict__ degI, const float* __restrict__ Wt,
    const float* __restrict__ bs, float* __restrict__ h1) {
  __shared__ float vs[128];
  int n = blockIdx.x, t = threadIdx.x;
  float sc = rsqrtf(fmaxf(degI[n], 1.f));
  vs[t] = agg[(size_t)n * 128 + t] * sc;
  __syncthreads();
  float acc = bs[t];
#pragma unroll 8
  for (int d = 0; d < 128; ++d) acc = fmaf(vs[d], Wt[d * 128 + t], acc);
  h1[(size_t)n * 128 + t] = fmaxf(acc, 0.f);
}
__global__ __launch_bounds__(128) void k_gc2b(const float* __restrict__ agg,
    const float* __restrict__ degI, const float* __restrict__ Wt,
    const float* __restrict__ bs, float* __restrict__ h2) {
  __shared__ float vs[128];
  int n = blockIdx.x, t = threadIdx.x;
  float sc = rsqrtf(fmaxf(degI[n], 1.f));
  vs[t] = agg[(size_t)n * 128 + t] * sc;
  __syncthreads();
  if (t < 8) {
    float acc = bs[t];
#pragma unroll 8
    for (int d = 0; d < 128; ++d) acc = fmaf(vs[d], Wt[d * 8 + t], acc);
    h2[(size_t)n * 8 + t] = acc;   // no relu
  }
}
__global__ __launch_bounds__(128) void k_e12(const float* __restrict__ ef,
    const float* __restrict__ W1, const float* __restrict__ b1,
    const float* __restrict__ W2, const float* __restrict__ b2,
    float* __restrict__ e2) {
  __shared__ float efs[128];
  __shared__ float t1s[128];
  int t = threadIdx.x;
  for (int it = 0; it < 16; ++it) {
    int b = blockIdx.x * 16 + it;
    efs[t] = ef[(size_t)b * 128 + t];
    __syncthreads();
    float acc = b1[t];
#pragma unroll 8
    for (int d = 0; d < 128; ++d) acc = fmaf(efs[d], W1[d * 128 + t], acc);
    t1s[t] = fmaxf(acc, 0.f);
    __syncthreads();
    if (t < 8) {
      float a2 = b2[t];
#pragma unroll 8
      for (int h = 0; h < 128; ++h) a2 = fmaf(t1s[h], W2[h * 8 + t], a2);
      e2[(size_t)b * 8 + t] = fmaxf(a2, 0.f);
    }
    __syncthreads();
  }
}

// ---------- fused conv + fc1 GEMM (counted-vmcnt pipeline) ----------
// BM=128, BN=256, BK=32; grid 1024 (32-way split-K); 8 waves (2Mx4N), 64x64/wave.
// LDS 64KB: A ring[2]x8KB + B ring[3]x16KB. Raw s_barrier with lgkmcnt(0)+vmcnt(6)
// only -- never vmcnt(0) -- so S(ss+2)'s 2 gload_lds + L(ss+2)'s 4 att loads stay
// in flight across every barrier (T4). Invariants:
//  - computeA(ss+1) uses W(ss+1) regs; its mandatory wait implies S(ss+1) complete
//    (issued before L(ss+1); vmcnt retires in order) => B(ss+1) staged pre-barrier.
//  - B slot (ss+2)%3 was drained at the end of step ss-1 (lgkm0+barrier) before
//    S(ss+2) is issued in step ss. A slot (ss+1)&1 likewise drained in step ss-1.
#define NS 64
struct Win { u16x8 a0, b0; uint16_t ae, be; };

__global__ __launch_bounds__(512, 4) void k_gemm(const uint16_t* __restrict__ W1s,
    const uint16_t* __restrict__ att, const float* __restrict__ conv_w,
    const float* __restrict__ conv_b, float* __restrict__ out1) {
  __shared__ __align__(16) char smem[65536];
  char* Abuf = smem;            // [2][8192]   A-tile [128m][32k] bf16, S64-swizzled
  char* Bbuf = smem + 16384;    // [3][16384]  W chunk [256n][32k], pre-swizzled global

  const int tid = threadIdx.x;
  const int lane = tid & 63, ln15 = lane & 15, g = lane >> 4;
  const int wid = tid >> 6, wm = wid >> 2, wn = wid & 3;
  const int bid = blockIdx.x;
  const int i_row = bid & 7, oh = (bid >> 3) & 1, jh = (bid >> 4) & 1;
  const int btile = bid >> 5;
  const int b0 = btile * 128;
  const int am = tid >> 2, ag = tid & 3;   // A-gen: row am (0..127), k-octet ag (0..3)

  f32x4 acc[4][4];
#pragma unroll
  for (int mt = 0; mt < 4; ++mt)
#pragma unroll
    for (int nt = 0; nt < 4; ++nt) { f32x4 z = {0.f, 0.f, 0.f, 0.f}; acc[mt][nt] = z; }

  auto loadWin = [&](int ss) {
    int jg = jh * 2 + (ss & 1);
    int j0 = jg * 32 + ag * 8;
    const uint16_t* r0 = att + ((size_t)(b0 + am) * 9 + i_row) * ATT_ROW + j0;
    const uint16_t* r1 = r0 + ATT_ROW;
    Win w;
    w.a0 = *(const u16x8*)r0; w.ae = r0[8];
    w.b0 = *(const u16x8*)r1; w.be = r1[8];
    return w;
  };

  auto computeA = [&](const Win& w, int ss, char* Ab) {
    float t0[9], t1[9];
#pragma unroll
    for (int e = 0; e < 8; ++e) {
      t0[e] = bf2f((uint16_t)w.a0[e]);
      t1[e] = bf2f((uint16_t)w.b0[e]);
    }
    t0[8] = bf2f(w.ae); t1[8] = bf2f(w.be);
    int o = oh * 32 + (ss >> 1);
    float c0  = conv_b[o];
    float k00 = conv_w[o * 4 + 0], k01 = conv_w[o * 4 + 1];
    float k10 = conv_w[o * 4 + 2], k11 = conv_w[o * 4 + 3];
    uint32_t pk[4];
#pragma unroll
    for (int e2 = 0; e2 < 8; e2 += 2) {
      float v0 = fmaf(k00, t0[e2],     fmaf(k01, t0[e2 + 1], fmaf(k10, t1[e2],     fmaf(k11, t1[e2 + 1], c0))));
      float v1 = fmaf(k00, t0[e2 + 1], fmaf(k01, t0[e2 + 2], fmaf(k10, t1[e2 + 1], fmaf(k11, t1[e2 + 2], c0))));
      v0 = fmaxf(v0, 0.f); v1 = fmaxf(v1, 0.f);
      uint32_t pr;
      asm("v_cvt_pk_bf16_f32 %0, %1, %2" : "=v"(pr) : "v"(v0), "v"(v1));
      pk[e2 >> 1] = pr;
    }
    u32x4 wv; wv.x = pk[0]; wv.y = pk[1]; wv.z = pk[2]; wv.w = pk[3];
    *(u32x4*)(Ab + S64s(am * 64 + ag * 16)) = wv;
  };

  auto stageB = [&](int ss, char* Bb) {
    int jg = jh * 2 + (ss & 1);
    int c = (oh * 32 + (ss >> 1)) * 32 + i_row * 4 + jg;
    const char* gsrc = (const char*)W1s + (size_t)c * 16384;
#pragma unroll
    for (int it = 0; it < 2; ++it) {
      char* ldsb = Bb + (size_t)(it * 512 + (tid & ~63)) * 16;   // wave-uniform base
      cp16(ldsb, gsrc + (size_t)(it * 512 + tid) * 16);
    }
  };

  auto mfmaStep = [&](const char* Ab, const char* Bb) {
    bf16x8 bfr[4];
#pragma unroll
    for (int nt = 0; nt < 4; ++nt) {
      int n = wn * 64 + nt * 16 + ln15;
      bfr[nt] = *(const bf16x8*)(Bb + S64s(n * 64 + g * 16));
    }
    bf16x8 afr[4];
#pragma unroll
    for (int mt = 0; mt < 4; ++mt) {
      int m = wm * 64 + mt * 16 + ln15;
      afr[mt] = *(const bf16x8*)(Ab + S64s(m * 64 + g * 16));
    }
#pragma unroll
    for (int mt = 0; mt < 4; ++mt)
#pragma unroll
      for (int nt = 0; nt < 4; ++nt)
        acc[mt][nt] = __builtin_amdgcn_mfma_f32_16x16x32_bf16(afr[mt], bfr[nt], acc[mt][nt], 0, 0, 0);
  };

  // ---- prologue: stage B(0),B(1); build A(0); preload W(1) ----
  stageB(0, Bbuf);
  stageB(1, Bbuf + 16384);
  Win w0 = loadWin(0);
  computeA(w0, 0, Abuf);              // mandatory wait drains prologue loads (once)
  Win wc = loadWin(1);                // W(1) for step 0's computeA
  asm volatile("s_waitcnt lgkmcnt(0)" ::: "memory");
  __builtin_amdgcn_sched_barrier(0);
  __builtin_amdgcn_s_barrier();
  __builtin_amdgcn_sched_barrier(0);

#pragma unroll 1
  for (int ss = 0; ss < NS; ++ss) {
    if (ss + 2 < NS) stageB(ss + 2, Bbuf + ((ss + 2) % 3) * 16384);   // 2 vm
    Win wn = wc;
    if (ss + 2 < NS) wn = loadWin(ss + 2);                            // 4 vm
    if (ss + 1 < NS) computeA(wc, ss + 1, Abuf + ((ss + 1) & 1) * 8192);
    wc = wn;
    mfmaStep(Abuf + (ss & 1) * 8192, Bbuf + (ss % 3) * 16384);
    // keep S(ss+2)+L(ss+2) (6 vm ops) in flight across the barrier; drain LDS ops
    asm volatile("s_waitcnt vmcnt(6)" ::: "memory");
    asm volatile("s_waitcnt lgkmcnt(0)" ::: "memory");
    __builtin_amdgcn_sched_barrier(0);
    __builtin_amdgcn_s_barrier();
    __builtin_amdgcn_sched_barrier(0);
  }

  // epilogue: split-K accumulate (32 partial adds per out element)
  const int rbase = b0 + wm * 64 + (lane >> 4) * 4;
  const int cbase = wn * 64 + ln15;
#pragma unroll
  for (int mt = 0; mt < 4; ++mt)
#pragma unroll
    for (int nt = 0; nt < 4; ++nt)
#pragma unroll
      for (int r = 0; r < 4; ++r)
        atomicAdd(out1 + (size_t)(rbase + mt * 16 + r) * 256 + cbase + nt * 16,
                  acc[mt][nt][r]);
}

// ---------- final: bias+relu, fc2, node_feats, fc3 ----------
__global__ __launch_bounds__(512) void k_fin(const float* __restrict__ out1,
    const float* __restrict__ fc1_b, const float* __restrict__ fc2_W,
    const float* __restrict__ fc2_b, const float* __restrict__ fc3_W,
    const float* __restrict__ fc3_b, const int* __restrict__ src,
    const int* __restrict__ dst, const float* __restrict__ h2,
    const float* __restrict__ e2, float* __restrict__ outp) {
  int lane = threadIdx.x & 63, w = threadIdx.x >> 6;
  int b  = blockIdx.x * 8 + w;
  int bu = __builtin_amdgcn_readfirstlane(b);
  f32x4 o4 = ((const f32x4*)(out1 + (size_t)bu * 256))[lane];
  f32x4 bi = ((const f32x4*)fc1_b)[lane];
  float v[4];
#pragma unroll
  for (int r = 0; r < 4; ++r) v[r] = fmaxf(o4[r] + bi[r], 0.f);
  float a24[24];
#pragma unroll
  for (int q = 0; q < 24; ++q) a24[q] = 0.f;
#pragma unroll
  for (int r = 0; r < 4; ++r) {
    const float* wr = fc2_W + (size_t)(lane * 4 + r) * 24;
#pragma unroll
    for (int q = 0; q < 24; ++q) a24[q] = fmaf(v[r], wr[q], a24[q]);
  }
#pragma unroll
  for (int q = 0; q < 24; ++q) {
    float t = a24[q];
    t += __shfl_xor(t, 1);  t += __shfl_xor(t, 2);  t += __shfl_xor(t, 4);
    t += __shfl_xor(t, 8);  t += __shfl_xor(t, 16); t += __shfl_xor(t, 32);
    a24[q] = fmaxf(t + fc2_b[q], 0.f);
  }
  int s = src[bu], d2 = dst[bu];
  float nf[24];
#pragma unroll
  for (int q = 0; q < 8; ++q) {
    float hs = h2[(size_t)s * 8 + q];
    float hd = h2[(size_t)d2 * 8 + q];
    nf[q] = hs; nf[8 + q] = hd; nf[16 + q] = hs + hd + e2[(size_t)bu * 8 + q];
  }
  if (lane == 0) {
#pragma unroll
    for (int c = 0; c < 2; ++c) {
      float r = fc3_b[c];
#pragma unroll
      for (int q = 0; q < 24; ++q) r = fmaf(a24[q], fc3_W[q * 2 + c], r);
#pragma unroll
      for (int q = 0; q < 24; ++q) r = fmaf(nf[q], fc3_W[(24 + q) * 2 + c], r);
      outp[(size_t)bu * 2 + c] = r;
    }
  }
}

// ---------- launch ----------
extern "C" void kernel_launch(void* const* d_in, const int* in_sizes, int n_in,
                              void* d_out, int out_size, void* d_ws, size_t ws_size,
                              hipStream_t stream) {
  const float* X         = (const float*)d_in[0];
  const int*   src       = (const int*)d_in[1];
  const int*   dst       = (const int*)d_in[2];
  const float* node_feat = (const float*)d_in[3];
  const float* edge_feat = (const float*)d_in[4];
  const float* attn_W    = (const float*)d_in[5];
  const float* attn_U    = (const float*)d_in[6];
  const float* attn_V    = (const float*)d_in[7];
  const float* conv_w    = (const float*)d_in[8];
  const float* conv_b    = (const float*)d_in[9];
  const float* gc1_W     = (const float*)d_in[10];
  const float* gc1_b     = (const float*)d_in[11];
  const float* gc2_W     = (const float*)d_in[12];
  const float* gc2_b     = (const float*)d_in[13];
  const float* lin1_W    = (const float*)d_in[14];
  const float* lin1_b    = (const float*)d_in[15];
  const float* lin2_W    = (const float*)d_in[16];
  const float* lin2_b    = (const float*)d_in[17];
  const float* fc1_W     = (const float*)d_in[18];
  const float* fc1_b     = (const float*)d_in[19];
  const float* fc2_W     = (const float*)d_in[20];
  const float* fc2_b     = (const float*)d_in[21];
  const float* fc3_W     = (const float*)d_in[22];
  const float* fc3_b     = (const float*)d_in[23];

  char* ws = (char*)d_ws;
  float*    out1 = (float*)(ws + 0);               // 4096*256*4      = 4,194,304
  float*    agg1 = (float*)(ws + 4194304);         // 2048*128*4      = 1,048,576
  float*    agg2 = (float*)(ws + 5242880);         // 2048*128*4      = 1,048,576
  float*    degO = (float*)(ws + 6291456);         // 2048*4
  float*    degI = (float*)(ws + 6299648);         // 2048*4
  uint16_t* W1s  = (uint16_t*)(ws + 6307840);      // 65536*256*2     = 33,554,432
  uint16_t* att  = (uint16_t*)(ws + 39862272);     // 4096*9*136*2    = 10,027,008
  float*    h1   = (float*)(ws + 49889280);        // 2048*128*4
  float*    h2   = (float*)(ws + 50937856);        // 2048*8*4
  float*    e2   = (float*)(ws + 51003392);        // 4096*8*4

  hipMemsetAsync(d_ws, 0, 6307840, stream);        // out1, agg1, agg2, degs

  k_prep<<<dim3(2048), dim3(256), 0, stream>>>(fc1_W, W1s);
  k_att <<<dim3(256),  dim3(512), 0, stream>>>(X, attn_W, attn_U, attn_V, att);
  k_deg <<<dim3(16),   dim3(256), 0, stream>>>(src, dst, degO, degI);
  k_gca <<<dim3(2048), dim3(256), 0, stream>>>(node_feat, src, dst, degO, agg1);
  k_gc1b<<<dim3(2048), dim3(128), 0, stream>>>(agg1, degI, gc1_W, gc1_b, h1);
  k_gca <<<dim3(2048), dim3(256), 0, stream>>>(h1, src, dst, degO, agg2);
  k_gc2b<<<dim3(2048), dim3(128), 0, stream>>>(agg2, degI, gc2_W, gc2_b, h2);
  k_e12 <<<dim3(256),  dim3(128), 0, stream>>>(edge_feat, lin1_W, lin1_b, lin2_W, lin2_b, e2);
  k_gemm<<<dim3(1024), dim3(512), 0, stream>>>(W1s, att, conv_w, conv_b, out1);
  k_fin <<<dim3(512),  dim3(512), 0, stream>>>(out1, fc1_b, fc2_W, fc2_b, fc3_W, fc3_b,
                                               src, dst, h2, e2, (float*)d_out);
}

// Round 6
// 520.448 us; speedup vs baseline: 3.3609x; 1.0646x over previous
//
#include <hip/hip_runtime.h>
#include <stdint.h>
#include <stddef.h>

typedef float    f32x4  __attribute__((ext_vector_type(4)));
typedef short    bf16x8 __attribute__((ext_vector_type(8)));
typedef uint16_t u16x8  __attribute__((ext_vector_type(8)));
typedef uint32_t u32x4  __attribute__((ext_vector_type(4)));

#define ATT_ROW 136   // 128 data + 8 zero pad (=> 272B rows, 16B aligned)

// ---------- helpers ----------
__device__ __forceinline__ uint16_t f2bf(float x) {
  union { float f; uint32_t u; } c; c.f = x;
  return (uint16_t)((c.u + 0x7FFFu + ((c.u >> 16) & 1u)) >> 16);  // RNE
}
__device__ __forceinline__ float bf2f(uint16_t h) {
  union { uint32_t u; float f; } c; c.u = ((uint32_t)h) << 16;
  return c.f;
}
// XOR swizzle for 64B-row tiles: byte a -> a ^ (((a>>6)&7)<<4). Bijective;
// write+read both apply it; k_prep stores the explicit inverse in global.
__device__ __forceinline__ int S64s(int a) { return a ^ (((a >> 6) & 7) << 4); }

__device__ __forceinline__ float fast_tanh(float t) {
  float r = __expf(-2.f * t);
  return 1.f - 2.f * r / (1.f + r);
}

// ---------- prep: fc1_W (fp32 [65536][256]) -> bf16 chunked column-major, swizzled ----------
__global__ __launch_bounds__(256) void k_prep(const float* __restrict__ W1,
                                              uint16_t* __restrict__ W1s) {
  __shared__ float st[32 * 256];
  const int c = blockIdx.x, tid = threadIdx.x;
  const float* src = W1 + (size_t)c * 32 * 256;
#pragma unroll
  for (int it = 0; it < 8; ++it) {
    int u = it * 256 + tid;
    ((f32x4*)st)[u] = ((const f32x4*)src)[u];
  }
  __syncthreads();
  uint16_t* dstc = W1s + (size_t)c * 8192;
#pragma unroll
  for (int q = 0; q < 4; ++q) {
    int p  = q * 256 + tid;       // 16B unit 0..1023
    int Np = p >> 2, Gp = p & 3;
    int n  = Np ^ ((Np >> 2) & 1);   // invert S64
    int g  = Gp ^ (n & 3);
    uint32_t w[4];
#pragma unroll
    for (int e2 = 0; e2 < 4; ++e2) {
      uint16_t lo = f2bf(st[(g * 8 + 2 * e2) * 256 + n]);
      uint16_t hi = f2bf(st[(g * 8 + 2 * e2 + 1) * 256 + n]);
      w[e2] = (uint32_t)lo | ((uint32_t)hi << 16);
    }
    u32x4 v; v.x = w[0]; v.y = w[1]; v.z = w[2]; v.w = w[3];
    *(u32x4*)(dstc + (size_t)p * 8) = v;
  }
}

// ---------- attention ----------
__global__ __launch_bounds__(512) void k_att(const float* __restrict__ X,
    const float* __restrict__ aW, const float* __restrict__ aU,
    const float* __restrict__ aV, uint16_t* __restrict__ att) {
  __shared__ float sa[8][8][66];
  __shared__ float su[8][8][66];
  __shared__ float sal[8][64];
  __shared__ float sv[64];
  const int tid = threadIdx.x, lane = tid & 63, w = tid >> 6;
  if (tid < 64) sv[tid] = aV[tid];
  __syncthreads();
  for (int rep = 0; rep < 2; ++rep) {
    int b  = blockIdx.x * 16 + w * 2 + rep;
    int bu = __builtin_amdgcn_readfirstlane(b);
    const float* xb = X + (size_t)bu * 512;
    float xi[8];
#pragma unroll
    for (int i = 0; i < 8; ++i) xi[i] = xb[i * 64 + lane];
    float a[8], u[8];
#pragma unroll
    for (int i = 0; i < 8; ++i) { a[i] = 0.f; u[i] = 0.f; }
#pragma unroll
    for (int f = 0; f < 64; ++f) {
      float wf = aW[f * 64 + lane];
      float uf = aU[f * 64 + lane];
#pragma unroll
      for (int i = 0; i < 8; ++i) {
        float xs = xb[i * 64 + f];      // wave-uniform -> s_load
        a[i] = fmaf(xs, wf, a[i]);
        u[i] = fmaf(xs, uf, u[i]);
      }
    }
#pragma unroll
    for (int i = 0; i < 8; ++i) { sa[w][i][lane] = a[i]; su[w][i][lane] = u[i]; }
    __syncthreads();
    int i2 = lane >> 3, j2 = lane & 7;
    float ev = 0.f;
#pragma unroll
    for (int h = 0; h < 64; ++h)
      ev = fmaf(fast_tanh(sa[w][i2][h] + su[w][j2][h]), sv[h], ev);
    float m = ev;
    m = fmaxf(m, __shfl_xor(m, 1));
    m = fmaxf(m, __shfl_xor(m, 2));
    m = fmaxf(m, __shfl_xor(m, 4));
    float p = __expf(ev - m);
    float s = p;
    s += __shfl_xor(s, 1); s += __shfl_xor(s, 2); s += __shfl_xor(s, 4);
    sal[w][lane] = p / s;
    __syncthreads();
#pragma unroll
    for (int i = 0; i < 8; ++i) {
      float c = 0.f;
#pragma unroll
      for (int j = 0; j < 8; ++j) c = fmaf(sal[w][i * 8 + j], xi[j], c);
      c = fmaf(-sal[w][i * 8 + i], xi[i], c);
      size_t ro = ((size_t)b * 9 + i) * ATT_ROW;
      att[ro + lane]      = f2bf(xi[i]);
      att[ro + 64 + lane] = f2bf(c);
      if (lane < 8) att[ro + 128 + lane] = 0;
    }
    {
      size_t ro = ((size_t)b * 9 + 8) * ATT_ROW;
      att[ro + lane] = 0; att[ro + 64 + lane] = 0;
      if (lane < 8) att[ro + 128 + lane] = 0;
    }
    __syncthreads();
  }
}

// ---------- graph path ----------
__global__ void k_deg(const int* __restrict__ src, const int* __restrict__ dst,
                      float* degO, float* degI) {
  int t = blockIdx.x * 256 + threadIdx.x;
  if (t < 4096) {
    atomicAdd(degO + src[t], 1.f);
    atomicAdd(degI + dst[t], 1.f);
  }
}
__global__ __launch_bounds__(256) void k_gca(const float* __restrict__ h,
    const int* __restrict__ src, const int* __restrict__ dst,
    const float* __restrict__ degO, float* __restrict__ agg) {
  int t = blockIdx.x * 256 + threadIdx.x;   // 4096*128
  int e = t >> 7, d = t & 127;
  int s = src[e];
  float sc = rsqrtf(fmaxf(degO[s], 1.f));
  atomicAdd(agg + (size_t)dst[e] * 128 + d, h[(size_t)s * 128 + d] * sc);
}
__global__ __launch_bounds__(128) void k_gc1b(const float* __restrict__ agg,
    const float* __restrict__ degI, const float* __restrict__ Wt,
    const float* __restrict__ bs, float* __restrict__ h1) {
  __shared__ float vs[128];
  int n = blockIdx.x, t = threadIdx.x;
  float sc = rsqrtf(fmaxf(degI[n], 1.f));
  vs[t] = agg[(size_t)n * 128 + t] * sc;
  __syncthreads();
  float acc = bs[t];
#pragma unroll 8
  for (int d = 0; d < 128; ++d) acc = fmaf(vs[d], Wt[d * 128 + t], acc);
  h1[(size_t)n * 128 + t] = fmaxf(acc, 0.f);
}
__global__ __launch_bounds__(128) void k_gc2b(const float* __restrict__ agg,
    const float* __restrict__ degI, const float* __restrict__ Wt,
    const float* __restrict__ bs, float* __restrict__ h2) {
  __shared__ float vs[128];
  int n = blockIdx.x, t = threadIdx.x;
  float sc = rsqrtf(fmaxf(degI[n], 1.f));
  vs[t] = agg[(size_t)n * 128 + t] * sc;
  __syncthreads();
  if (t < 8) {
    float acc = bs[t];
#pragma unroll 8
    for (int d = 0; d < 128; ++d) acc = fmaf(vs[d], Wt[d * 8 + t], acc);
    h2[(size_t)n * 8 + t] = acc;   // no relu
  }
}
__global__ __launch_bounds__(128) void k_e12(const float* __restrict__ ef,
    const float* __restrict__ W1, const float* __restrict__ b1,
    const float* __restrict__ W2, const float* __restrict__ b2,
    float* __restrict__ e2) {
  __shared__ float efs[128];
  __shared__ float t1s[128];
  int t = threadIdx.x;
  for (int it = 0; it < 16; ++it) {
    int b = blockIdx.x * 16 + it;
    efs[t] = ef[(size_t)b * 128 + t];
    __syncthreads();
    float acc = b1[t];
#pragma unroll 8
    for (int d = 0; d < 128; ++d) acc = fmaf(efs[d], W1[d * 128 + t], acc);
    t1s[t] = fmaxf(acc, 0.f);
    __syncthreads();
    if (t < 8) {
      float a2 = b2[t];
#pragma unroll 8
      for (int h = 0; h < 128; ++h) a2 = fmaf(t1s[h], W2[h * 8 + t], a2);
      e2[(size_t)b * 8 + t] = fmaxf(a2, 0.f);
    }
    __syncthreads();
  }
}

// ---------- fused conv + fc1 GEMM (B direct global->reg; A-only LDS) ----------
// BM=128, BN=256, BK=64; grid 512 = (i 0..7)|(oh<<3)|(btile<<4); 16-way split-K.
// 8 waves 2Mx4N, 64x64/wave, acc = 64 AGPR. B fragments load straight from the
// pre-swizzled W1s (one 16B unit per lane), double-banked bA/bB across steps ->
// zero B LDS traffic, and barriers only order the 16KB A tile (lgkmcnt(0) only;
// no vmcnt at barriers at all). A: 2-ring x 16KB (2 panels x 8KB [128][32]).
__global__ __launch_bounds__(512) void k_gemm(const uint16_t* __restrict__ W1s,
    const uint16_t* __restrict__ att, const float* __restrict__ conv_w,
    const float* __restrict__ conv_b, float* __restrict__ out1) {
  __shared__ __align__(16) char smem[32768];   // A ring: slot s at s*16384, panel kk at +kk*8192

  const int tid = threadIdx.x;
  const int lane = tid & 63, ln15 = lane & 15, g = lane >> 4;
  const int wid = tid >> 6, wm = wid >> 2, wvn = wid & 3;
  const int bid = blockIdx.x;
  const int i_row = bid & 7, oh = (bid >> 3) & 1;
  const int btile = bid >> 4;          // 32 btiles
  const int b0 = btile * 128;
  const int am = tid >> 2, ag = tid & 3;   // A-gen: row am, 16-k group ag

  // ---- hoisted invariants ----
  const uint16_t* rb = att + ((size_t)(b0 + am) * 9 + i_row) * ATT_ROW + ag * 16;
  const char* W1c = (const char*)W1s + ((size_t)(oh * 32) * 32 + i_row * 4) * 16384;
  int voff[4], aro[4];
#pragma unroll
  for (int nt = 0; nt < 4; ++nt)
    voff[nt] = S64s((wvn * 64 + nt * 16 + ln15) * 64 + g * 16);
#pragma unroll
  for (int mt = 0; mt < 4; ++mt)
    aro[mt] = S64s((wm * 64 + mt * 16 + ln15) * 64 + g * 16);
  const int aw0 = (ag >> 1) * 8192 + S64s(am * 64 + (ag & 1) * 32);

  f32x4 acc[4][4];
#pragma unroll
  for (int mt = 0; mt < 4; ++mt)
#pragma unroll
    for (int nt = 0; nt < 4; ++nt) { f32x4 z = {0.f, 0.f, 0.f, 0.f}; acc[mt][nt] = z; }

  struct Win { u16x8 a0, a1, b0, b1; uint16_t ae, be; };
  auto loadWin = [&](int h) {
    const uint16_t* r0 = rb + h * 64;
    const uint16_t* r1 = r0 + ATT_ROW;
    Win w;
    w.a0 = *(const u16x8*)r0; w.a1 = *(const u16x8*)(r0 + 8); w.ae = r0[16];
    w.b0 = *(const u16x8*)r1; w.b1 = *(const u16x8*)(r1 + 8); w.be = r1[16];
    return w;
  };

  auto computeA = [&](const Win& w, int o, char* As) {
    float t0[17], t1[17];
#pragma unroll
    for (int e = 0; e < 8; ++e) {
      t0[e] = bf2f((uint16_t)w.a0[e]); t0[e + 8] = bf2f((uint16_t)w.a1[e]);
      t1[e] = bf2f((uint16_t)w.b0[e]); t1[e + 8] = bf2f((uint16_t)w.b1[e]);
    }
    t0[16] = bf2f(w.ae); t1[16] = bf2f(w.be);
    float c0  = conv_b[o];
    float k00 = conv_w[o * 4 + 0], k01 = conv_w[o * 4 + 1];
    float k10 = conv_w[o * 4 + 2], k11 = conv_w[o * 4 + 3];
    uint32_t pk[8];
#pragma unroll
    for (int e2 = 0; e2 < 16; e2 += 2) {
      float v0 = fmaf(k00, t0[e2],     fmaf(k01, t0[e2 + 1], fmaf(k10, t1[e2],     fmaf(k11, t1[e2 + 1], c0))));
      float v1 = fmaf(k00, t0[e2 + 1], fmaf(k01, t0[e2 + 2], fmaf(k10, t1[e2 + 1], fmaf(k11, t1[e2 + 2], c0))));
      v0 = fmaxf(v0, 0.f); v1 = fmaxf(v1, 0.f);
      uint32_t pr;
      asm("v_cvt_pk_bf16_f32 %0, %1, %2" : "=v"(pr) : "v"(v0), "v"(v1));
      pk[e2 >> 1] = pr;
    }
    u32x4 wv0; wv0.x = pk[0]; wv0.y = pk[1]; wv0.z = pk[2]; wv0.w = pk[3];
    u32x4 wv1; wv1.x = pk[4]; wv1.y = pk[5]; wv1.z = pk[6]; wv1.w = pk[7];
    *(u32x4*)(As + aw0)        = wv0;
    *(u32x4*)(As + (aw0 ^ 16)) = wv1;
  };

  auto mfmaStep = [&](const char* As, const bf16x8* bank) {
#pragma unroll
    for (int kk = 0; kk < 2; ++kk) {
      bf16x8 afr[4];
#pragma unroll
      for (int mt = 0; mt < 4; ++mt)
        afr[mt] = *(const bf16x8*)(As + kk * 8192 + aro[mt]);
#pragma unroll
      for (int mt = 0; mt < 4; ++mt)
#pragma unroll
        for (int nt = 0; nt < 4; ++nt)
          acc[mt][nt] = __builtin_amdgcn_mfma_f32_16x16x32_bf16(afr[mt], bank[kk * 4 + nt], acc[mt][nt], 0, 0, 0);
    }
  };

  bf16x8 bA[8], bB[8];
  Win winC, winN;

  // ---- prologue: bfr(0)->bA, A(0)->slot0, W(1)->winC ----
#pragma unroll
  for (int nt = 0; nt < 4; ++nt) {
    bA[nt]     = *(const bf16x8*)(W1c + voff[nt]);
    bA[4 + nt] = *(const bf16x8*)(W1c + 16384 + voff[nt]);
  }
  {
    Win w0 = loadWin(0);
    computeA(w0, oh * 32, smem);           // reg-wait drains prologue loads once
  }
  winC = loadWin(1);
  winN = winC;
  asm volatile("s_waitcnt lgkmcnt(0)" ::: "memory");
  __builtin_amdgcn_sched_barrier(0);
  __builtin_amdgcn_s_barrier();
  __builtin_amdgcn_sched_barrier(0);

#define GEMM_STEP(CUR, NXT, CB1, H2, O1, ARD, AWR, DO_L)                         \
  {                                                                              \
    _Pragma("unroll") for (int nt = 0; nt < 4; ++nt) {                           \
      NXT[nt]     = *(const bf16x8*)((CB1) + voff[nt]);                          \
      NXT[4 + nt] = *(const bf16x8*)((CB1) + 16384 + voff[nt]);                  \
    }                                                                            \
    if (DO_L) winN = loadWin(H2);                                                \
    computeA(winC, (O1), (AWR));                                                 \
    winC = winN;                                                                 \
    mfmaStep((ARD), CUR);                                                        \
    asm volatile("s_waitcnt lgkmcnt(0)" ::: "memory");                           \
    __builtin_amdgcn_sched_barrier(0);                                           \
    __builtin_amdgcn_s_barrier();                                                \
    __builtin_amdgcn_sched_barrier(0);                                           \
  }

  const char* cb = W1c;          // chunk base for current o'
  int oc = oh * 32;
#pragma unroll 1
  for (int it = 0; it < 31; ++it) {
    // ss = 2*it   (read A slot0, bank bA; build A(ss+1) in slot1; bfr(ss+1) h=1 same o')
    GEMM_STEP(bA, bB, cb + 32768, 0, oc, smem, smem + 16384, 1)
    // ss = 2*it+1 (read A slot1, bank bB; build A(ss+2) in slot0; bfr(ss+2) next o' h=0)
    GEMM_STEP(bB, bA, cb + 524288, 1, oc + 1, smem + 16384, smem, 1)
    cb += 524288;
    ++oc;
  }
  // ---- peel ss=62 ----
  {
#pragma unroll
    for (int nt = 0; nt < 4; ++nt) {
      bB[nt]     = *(const bf16x8*)(cb + 32768 + voff[nt]);
      bB[4 + nt] = *(const bf16x8*)(cb + 32768 + 16384 + voff[nt]);
    }
    computeA(winC, oh * 32 + 31, smem + 16384);
    mfmaStep(smem, bA);
    asm volatile("s_waitcnt lgkmcnt(0)" ::: "memory");
    __builtin_amdgcn_sched_barrier(0);
    __builtin_amdgcn_s_barrier();
    __builtin_amdgcn_sched_barrier(0);
  }
  // ---- ss=63 ----
  mfmaStep(smem + 16384, bB);
#undef GEMM_STEP

  // epilogue: split-K accumulate (16 partial adds per out element)
  const int rbase = b0 + wm * 64 + (lane >> 4) * 4;
  const int cbase = wvn * 64 + ln15;
#pragma unroll
  for (int mt = 0; mt < 4; ++mt)
#pragma unroll
    for (int nt = 0; nt < 4; ++nt)
#pragma unroll
      for (int r = 0; r < 4; ++r)
        atomicAdd(out1 + (size_t)(rbase + mt * 16 + r) * 256 + cbase + nt * 16,
                  acc[mt][nt][r]);
}

// ---------- final: bias+relu, fc2, node_feats, fc3 ----------
__global__ __launch_bounds__(512) void k_fin(const float* __restrict__ out1,
    const float* __restrict__ fc1_b, const float* __restrict__ fc2_W,
    const float* __restrict__ fc2_b, const float* __restrict__ fc3_W,
    const float* __restrict__ fc3_b, const int* __restrict__ src,
    const int* __restrict__ dst, const float* __restrict__ h2,
    const float* __restrict__ e2, float* __restrict__ outp) {
  int lane = threadIdx.x & 63, w = threadIdx.x >> 6;
  int b  = blockIdx.x * 8 + w;
  int bu = __builtin_amdgcn_readfirstlane(b);
  f32x4 o4 = ((const f32x4*)(out1 + (size_t)bu * 256))[lane];
  f32x4 bi = ((const f32x4*)fc1_b)[lane];
  float v[4];
#pragma unroll
  for (int r = 0; r < 4; ++r) v[r] = fmaxf(o4[r] + bi[r], 0.f);
  float a24[24];
#pragma unroll
  for (int q = 0; q < 24; ++q) a24[q] = 0.f;
#pragma unroll
  for (int r = 0; r < 4; ++r) {
    const float* wr = fc2_W + (size_t)(lane * 4 + r) * 24;
#pragma unroll
    for (int q = 0; q < 24; ++q) a24[q] = fmaf(v[r], wr[q], a24[q]);
  }
#pragma unroll
  for (int q = 0; q < 24; ++q) {
    float t = a24[q];
    t += __shfl_xor(t, 1);  t += __shfl_xor(t, 2);  t += __shfl_xor(t, 4);
    t += __shfl_xor(t, 8);  t += __shfl_xor(t, 16); t += __shfl_xor(t, 32);
    a24[q] = fmaxf(t + fc2_b[q], 0.f);
  }
  int s = src[bu], d2 = dst[bu];
  float nf[24];
#pragma unroll
  for (int q = 0; q < 8; ++q) {
    float hs = h2[(size_t)s * 8 + q];
    float hd = h2[(size_t)d2 * 8 + q];
    nf[q] = hs; nf[8 + q] = hd; nf[16 + q] = hs + hd + e2[(size_t)bu * 8 + q];
  }
  if (lane == 0) {
#pragma unroll
    for (int c = 0; c < 2; ++c) {
      float r = fc3_b[c];
#pragma unroll
      for (int q = 0; q < 24; ++q) r = fmaf(a24[q], fc3_W[q * 2 + c], r);
#pragma unroll
      for (int q = 0; q < 24; ++q) r = fmaf(nf[q], fc3_W[(24 + q) * 2 + c], r);
      outp[(size_t)bu * 2 + c] = r;
    }
  }
}

// ---------- launch ----------
extern "C" void kernel_launch(void* const* d_in, const int* in_sizes, int n_in,
                              void* d_out, int out_size, void* d_ws, size_t ws_size,
                              hipStream_t stream) {
  const float* X         = (const float*)d_in[0];
  const int*   src       = (const int*)d_in[1];
  const int*   dst       = (const int*)d_in[2];
  const float* node_feat = (const float*)d_in[3];
  const float* edge_feat = (const float*)d_in[4];
  const float* attn_W    = (const float*)d_in[5];
  const float* attn_U    = (const float*)d_in[6];
  const float* attn_V    = (const float*)d_in[7];
  const float* conv_w    = (const float*)d_in[8];
  const float* conv_b    = (const float*)d_in[9];
  const float* gc1_W     = (const float*)d_in[10];
  const float* gc1_b     = (const float*)d_in[11];
  const float* gc2_W     = (const float*)d_in[12];
  const float* gc2_b     = (const float*)d_in[13];
  const float* lin1_W    = (const float*)d_in[14];
  const float* lin1_b    = (const float*)d_in[15];
  const float* lin2_W    = (const float*)d_in[16];
  const float* lin2_b    = (const float*)d_in[17];
  const float* fc1_W     = (const float*)d_in[18];
  const float* fc1_b     = (const float*)d_in[19];
  const float* fc2_W     = (const float*)d_in[20];
  const float* fc2_b     = (const float*)d_in[21];
  const float* fc3_W     = (const float*)d_in[22];
  const float* fc3_b     = (const float*)d_in[23];

  char* ws = (char*)d_ws;
  float*    out1 = (float*)(ws + 0);               // 4096*256*4      = 4,194,304
  float*    agg1 = (float*)(ws + 4194304);         // 2048*128*4      = 1,048,576
  float*    agg2 = (float*)(ws + 5242880);         // 2048*128*4      = 1,048,576
  float*    degO = (float*)(ws + 6291456);         // 2048*4
  float*    degI = (float*)(ws + 6299648);         // 2048*4
  uint16_t* W1s  = (uint16_t*)(ws + 6307840);      // 65536*256*2     = 33,554,432
  uint16_t* att  = (uint16_t*)(ws + 39862272);     // 4096*9*136*2    = 10,027,008
  float*    h1   = (float*)(ws + 49889280);        // 2048*128*4
  float*    h2   = (float*)(ws + 50937856);        // 2048*8*4
  float*    e2   = (float*)(ws + 51003392);        // 4096*8*4

  hipMemsetAsync(d_ws, 0, 6307840, stream);        // out1, agg1, agg2, degs

  k_prep<<<dim3(2048), dim3(256), 0, stream>>>(fc1_W, W1s);
  k_att <<<dim3(256),  dim3(512), 0, stream>>>(X, attn_W, attn_U, attn_V, att);
  k_deg <<<dim3(16),   dim3(256), 0, stream>>>(src, dst, degO, degI);
  k_gca <<<dim3(2048), dim3(256), 0, stream>>>(node_feat, src, dst, degO, agg1);
  k_gc1b<<<dim3(2048), dim3(128), 0, stream>>>(agg1, degI, gc1_W, gc1_b, h1);
  k_gca <<<dim3(2048), dim3(256), 0, stream>>>(h1, src, dst, degO, agg2);
  k_gc2b<<<dim3(2048), dim3(128), 0, stream>>>(agg2, degI, gc2_W, gc2_b, h2);
  k_e12 <<<dim3(256),  dim3(128), 0, stream>>>(edge_feat, lin1_W, lin1_b, lin2_W, lin2_b, e2);
  k_gemm<<<dim3(512),  dim3(512), 0, stream>>>(W1s, att, conv_w, conv_b, out1);
  k_fin <<<dim3(512),  dim3(512), 0, stream>>>(out1, fc1_b, fc2_W, fc2_b, fc3_W, fc3_b,
                                               src, dst, h2, e2, (float*)d_out);
}

// Round 7
// 492.793 us; speedup vs baseline: 3.5495x; 1.0561x over previous
//
#include <hip/hip_runtime.h>
#include <stdint.h>
#include <stddef.h>

typedef float    f32x4  __attribute__((ext_vector_type(4)));
typedef short    bf16x8 __attribute__((ext_vector_type(8)));
typedef uint16_t u16x8  __attribute__((ext_vector_type(8)));
typedef uint32_t u32x4  __attribute__((ext_vector_type(4)));
typedef const bf16x8 __attribute__((address_space(1))) *gcbf16x8;  // force global_load (not flat)

#define ATT_ROW 136   // 128 data + 8 zero pad (=> 272B rows, 16B aligned)

// ---------- helpers ----------
__device__ __forceinline__ uint16_t f2bf(float x) {
  union { float f; uint32_t u; } c; c.f = x;
  return (uint16_t)((c.u + 0x7FFFu + ((c.u >> 16) & 1u)) >> 16);  // RNE
}
__device__ __forceinline__ float bf2f(uint16_t h) {
  union { uint32_t u; float f; } c; c.u = ((uint32_t)h) << 16;
  return c.f;
}
// XOR swizzle for 64B-row tiles: byte a -> a ^ (((a>>6)&7)<<4). Bijective;
// write+read both apply it; k_prep stores the explicit inverse in global.
__device__ __forceinline__ int S64s(int a) { return a ^ (((a >> 6) & 7) << 4); }

__device__ __forceinline__ float fast_tanh(float t) {
  float r = __expf(-2.f * t);
  return 1.f - 2.f * r / (1.f + r);
}

// ---------- prep: fc1_W (fp32 [65536][256]) -> bf16 chunked column-major, swizzled ----------
__global__ __launch_bounds__(256) void k_prep(const float* __restrict__ W1,
                                              uint16_t* __restrict__ W1s) {
  __shared__ float st[32 * 256];
  const int c = blockIdx.x, tid = threadIdx.x;
  const float* src = W1 + (size_t)c * 32 * 256;
#pragma unroll
  for (int it = 0; it < 8; ++it) {
    int u = it * 256 + tid;
    ((f32x4*)st)[u] = ((const f32x4*)src)[u];
  }
  __syncthreads();
  uint16_t* dstc = W1s + (size_t)c * 8192;
#pragma unroll
  for (int q = 0; q < 4; ++q) {
    int p  = q * 256 + tid;       // 16B unit 0..1023
    int Np = p >> 2, Gp = p & 3;
    int n  = Np ^ ((Np >> 2) & 1);   // invert S64
    int g  = Gp ^ (n & 3);
    uint32_t w[4];
#pragma unroll
    for (int e2 = 0; e2 < 4; ++e2) {
      uint16_t lo = f2bf(st[(g * 8 + 2 * e2) * 256 + n]);
      uint16_t hi = f2bf(st[(g * 8 + 2 * e2 + 1) * 256 + n]);
      w[e2] = (uint32_t)lo | ((uint32_t)hi << 16);
    }
    u32x4 v; v.x = w[0]; v.y = w[1]; v.z = w[2]; v.w = w[3];
    *(u32x4*)(dstc + (size_t)p * 8) = v;
  }
}

// ---------- attention ----------
__global__ __launch_bounds__(512) void k_att(const float* __restrict__ X,
    const float* __restrict__ aW, const float* __restrict__ aU,
    const float* __restrict__ aV, uint16_t* __restrict__ att) {
  __shared__ float sa[8][8][66];
  __shared__ float su[8][8][66];
  __shared__ float sal[8][64];
  __shared__ float sv[64];
  const int tid = threadIdx.x, lane = tid & 63, w = tid >> 6;
  if (tid < 64) sv[tid] = aV[tid];
  __syncthreads();
  for (int rep = 0; rep < 2; ++rep) {
    int b  = blockIdx.x * 16 + w * 2 + rep;
    int bu = __builtin_amdgcn_readfirstlane(b);
    const float* xb = X + (size_t)bu * 512;
    float xi[8];
#pragma unroll
    for (int i = 0; i < 8; ++i) xi[i] = xb[i * 64 + lane];
    float a[8], u[8];
#pragma unroll
    for (int i = 0; i < 8; ++i) { a[i] = 0.f; u[i] = 0.f; }
#pragma unroll
    for (int f = 0; f < 64; ++f) {
      float wf = aW[f * 64 + lane];
      float uf = aU[f * 64 + lane];
#pragma unroll
      for (int i = 0; i < 8; ++i) {
        float xs = xb[i * 64 + f];      // wave-uniform -> s_load
        a[i] = fmaf(xs, wf, a[i]);
        u[i] = fmaf(xs, uf, u[i]);
      }
    }
#pragma unroll
    for (int i = 0; i < 8; ++i) { sa[w][i][lane] = a[i]; su[w][i][lane] = u[i]; }
    __syncthreads();
    int i2 = lane >> 3, j2 = lane & 7;
    float ev = 0.f;
#pragma unroll
    for (int h = 0; h < 64; ++h)
      ev = fmaf(fast_tanh(sa[w][i2][h] + su[w][j2][h]), sv[h], ev);
    float m = ev;
    m = fmaxf(m, __shfl_xor(m, 1));
    m = fmaxf(m, __shfl_xor(m, 2));
    m = fmaxf(m, __shfl_xor(m, 4));
    float p = __expf(ev - m);
    float s = p;
    s += __shfl_xor(s, 1); s += __shfl_xor(s, 2); s += __shfl_xor(s, 4);
    sal[w][lane] = p / s;
    __syncthreads();
#pragma unroll
    for (int i = 0; i < 8; ++i) {
      float c = 0.f;
#pragma unroll
      for (int j = 0; j < 8; ++j) c = fmaf(sal[w][i * 8 + j], xi[j], c);
      c = fmaf(-sal[w][i * 8 + i], xi[i], c);
      size_t ro = ((size_t)b * 9 + i) * ATT_ROW;
      att[ro + lane]      = f2bf(xi[i]);
      att[ro + 64 + lane] = f2bf(c);
      if (lane < 8) att[ro + 128 + lane] = 0;
    }
    {
      size_t ro = ((size_t)b * 9 + 8) * ATT_ROW;
      att[ro + lane] = 0; att[ro + 64 + lane] = 0;
      if (lane < 8) att[ro + 128 + lane] = 0;
    }
    __syncthreads();
  }
}

// ---------- graph path ----------
__global__ void k_deg(const int* __restrict__ src, const int* __restrict__ dst,
                      float* degO, float* degI) {
  int t = blockIdx.x * 256 + threadIdx.x;
  if (t < 4096) {
    atomicAdd(degO + src[t], 1.f);
    atomicAdd(degI + dst[t], 1.f);
  }
}
__global__ __launch_bounds__(256) void k_gca(const float* __restrict__ h,
    const int* __restrict__ src, const int* __restrict__ dst,
    const float* __restrict__ degO, float* __restrict__ agg) {
  int t = blockIdx.x * 256 + threadIdx.x;   // 4096*128
  int e = t >> 7, d = t & 127;
  int s = src[e];
  float sc = rsqrtf(fmaxf(degO[s], 1.f));
  atomicAdd(agg + (size_t)dst[e] * 128 + d, h[(size_t)s * 128 + d] * sc);
}
__global__ __launch_bounds__(128) void k_gc1b(const float* __restrict__ agg,
    const float* __restrict__ degI, const float* __restrict__ Wt,
    const float* __restrict__ bs, float* __restrict__ h1) {
  __shared__ float vs[128];
  int n = blockIdx.x, t = threadIdx.x;
  float sc = rsqrtf(fmaxf(degI[n], 1.f));
  vs[t] = agg[(size_t)n * 128 + t] * sc;
  __syncthreads();
  float acc = bs[t];
#pragma unroll 8
  for (int d = 0; d < 128; ++d) acc = fmaf(vs[d], Wt[d * 128 + t], acc);
  h1[(size_t)n * 128 + t] = fmaxf(acc, 0.f);
}
__global__ __launch_bounds__(128) void k_gc2b(const float* __restrict__ agg,
    const float* __restrict__ degI, const float* __restrict__ Wt,
    const float* __restrict__ bs, float* __restrict__ h2) {
  __shared__ float vs[128];
  int n = blockIdx.x, t = threadIdx.x;
  float sc = rsqrtf(fmaxf(degI[n], 1.f));
  vs[t] = agg[(size_t)n * 128 + t] * sc;
  __syncthreads();
  if (t < 8) {
    float acc = bs[t];
#pragma unroll 8
    for (int d = 0; d < 128; ++d) acc = fmaf(vs[d], Wt[d * 8 + t], acc);
    h2[(size_t)n * 8 + t] = acc;   // no relu
  }
}
__global__ __launch_bounds__(128) void k_e12(const float* __restrict__ ef,
    const float* __restrict__ W1, const float* __restrict__ b1,
    const float* __restrict__ W2, const float* __restrict__ b2,
    float* __restrict__ e2) {
  __shared__ float efs[128];
  __shared__ float t1s[128];
  int t = threadIdx.x;
  for (int it = 0; it < 16; ++it) {
    int b = blockIdx.x * 16 + it;
    efs[t] = ef[(size_t)b * 128 + t];
    __syncthreads();
    float acc = b1[t];
#pragma unroll 8
    for (int d = 0; d < 128; ++d) acc = fmaf(efs[d], W1[d * 128 + t], acc);
    t1s[t] = fmaxf(acc, 0.f);
    __syncthreads();
    if (t < 8) {
      float a2 = b2[t];
#pragma unroll 8
      for (int h = 0; h < 128; ++h) a2 = fmaf(t1s[h], W2[h * 8 + t], a2);
      e2[(size_t)b * 8 + t] = fmaxf(a2, 0.f);
    }
    __syncthreads();
  }
}

// ---------- fused conv + fc1 GEMM ----------
// BM=128, BN=256, BK=64; grid 512 = (i 0..7)|(oh<<3)|(btile<<4); 16-way split-K.
// R7 changes vs R6 (step-body only; math/layout identical):
//  - att windows hoisted to persistent regs (wH0/wH1) -- no per-step att loads.
//  - conv consts prefetched one o ahead (cc/ccN) -- s_load latency off the lgkm path.
//  - B-bank fills via address_space(1) casts -> guaranteed global_load (vmcnt only).
//  - sched_group_barrier interleave {VMEM 8}{DSR 8}{VALU 14, MFMA 4}x8{DSW 2} so
//    conv-VALU co-issues with the MFMA pipe within each wave.
struct CC { float c0, k00, k01, k10, k11; };
struct Win { u16x8 a0, a1, b0, b1; uint16_t ae, be; };

__global__ __launch_bounds__(512) void k_gemm(const uint16_t* __restrict__ W1s,
    const uint16_t* __restrict__ att, const float* __restrict__ conv_w,
    const float* __restrict__ conv_b, float* __restrict__ out1) {
  __shared__ __align__(16) char smem[32768];   // A ring: slot s at s*16384, panel kk at +kk*8192

  const int tid = threadIdx.x;
  const int lane = tid & 63, ln15 = lane & 15, g = lane >> 4;
  const int wid = tid >> 6, wm = wid >> 2, wvn = wid & 3;
  const int bid = blockIdx.x;
  const int i_row = bid & 7, oh = (bid >> 3) & 1;
  const int btile = bid >> 4;          // 32 btiles
  const int b0 = btile * 128;
  const int am = tid >> 2, ag = tid & 3;   // A-gen: row am, 16-k group ag

  // ---- hoisted invariants ----
  const uint16_t* rb = att + ((size_t)(b0 + am) * 9 + i_row) * ATT_ROW + ag * 16;
  const char* W1c = (const char*)W1s + ((size_t)(oh * 32) * 32 + i_row * 4) * 16384;
  int voff[4], aro[4];
#pragma unroll
  for (int nt = 0; nt < 4; ++nt)
    voff[nt] = S64s((wvn * 64 + nt * 16 + ln15) * 64 + g * 16);
#pragma unroll
  for (int mt = 0; mt < 4; ++mt)
    aro[mt] = S64s((wm * 64 + mt * 16 + ln15) * 64 + g * 16);
  const int aw0 = (ag >> 1) * 8192 + S64s(am * 64 + (ag & 1) * 32);

  f32x4 acc[4][4];
#pragma unroll
  for (int mt = 0; mt < 4; ++mt)
#pragma unroll
    for (int nt = 0; nt < 4; ++nt) { f32x4 z = {0.f, 0.f, 0.f, 0.f}; acc[mt][nt] = z; }

  auto loadWin = [&](int h) {
    const uint16_t* r0 = rb + h * 64;
    const uint16_t* r1 = r0 + ATT_ROW;
    Win w;
    w.a0 = *(const u16x8*)r0; w.a1 = *(const u16x8*)(r0 + 8); w.ae = r0[16];
    w.b0 = *(const u16x8*)r1; w.b1 = *(const u16x8*)(r1 + 8); w.be = r1[16];
    return w;
  };
  auto loadCC = [&](int o) {
    CC c; c.c0 = conv_b[o];
    c.k00 = conv_w[o * 4 + 0]; c.k01 = conv_w[o * 4 + 1];
    c.k10 = conv_w[o * 4 + 2]; c.k11 = conv_w[o * 4 + 3];
    return c;
  };

// computeA body (produces wv0/wv1 + writes to AWR), used by prologue + steps
#define CA_BODY(WH, CCX, AWR)                                                      \
  {                                                                                \
    float t0[17], t1[17];                                                          \
    _Pragma("unroll") for (int e = 0; e < 8; ++e) {                                \
      t0[e] = bf2f((uint16_t)(WH).a0[e]); t0[e + 8] = bf2f((uint16_t)(WH).a1[e]);  \
      t1[e] = bf2f((uint16_t)(WH).b0[e]); t1[e + 8] = bf2f((uint16_t)(WH).b1[e]);  \
    }                                                                              \
    t0[16] = bf2f((WH).ae); t1[16] = bf2f((WH).be);                                \
    uint32_t pk[8];                                                                \
    _Pragma("unroll") for (int e2 = 0; e2 < 16; e2 += 2) {                         \
      float v0 = fmaf((CCX).k00, t0[e2], fmaf((CCX).k01, t0[e2 + 1],               \
                 fmaf((CCX).k10, t1[e2], fmaf((CCX).k11, t1[e2 + 1], (CCX).c0)))); \
      float v1 = fmaf((CCX).k00, t0[e2 + 1], fmaf((CCX).k01, t0[e2 + 2],           \
                 fmaf((CCX).k10, t1[e2 + 1], fmaf((CCX).k11, t1[e2 + 2], (CCX).c0))));\
      v0 = fmaxf(v0, 0.f); v1 = fmaxf(v1, 0.f);                                    \
      uint32_t pr;                                                                 \
      asm("v_cvt_pk_bf16_f32 %0, %1, %2" : "=v"(pr) : "v"(v0), "v"(v1));           \
      pk[e2 >> 1] = pr;                                                            \
    }                                                                              \
    u32x4 wv0; wv0.x = pk[0]; wv0.y = pk[1]; wv0.z = pk[2]; wv0.w = pk[3];         \
    u32x4 wv1; wv1.x = pk[4]; wv1.y = pk[5]; wv1.z = pk[6]; wv1.w = pk[7];         \
    *(u32x4*)((AWR) + aw0)        = wv0;                                           \
    *(u32x4*)((AWR) + (aw0 ^ 16)) = wv1;                                           \
  }

// full K-step: fill next B bank, ds_read A frags, conv-VALU for next A tile,
// 32 MFMA, A writes; SGB-interleaved; counted-lgkm barrier (A-tile ds ops only).
#define CSTEP(ARD, AWR, BANK, FILLB, FSRC, WH, CCX)                                \
  {                                                                                \
    _Pragma("unroll") for (int nt = 0; nt < 4; ++nt) {                             \
      FILLB[nt]     = *(gcbf16x8)((FSRC) + voff[nt]);                              \
      FILLB[4 + nt] = *(gcbf16x8)((FSRC) + 16384 + voff[nt]);                      \
    }                                                                              \
    bf16x8 afr[8];                                                                 \
    _Pragma("unroll") for (int kk = 0; kk < 2; ++kk)                               \
      _Pragma("unroll") for (int mt = 0; mt < 4; ++mt)                             \
        afr[kk * 4 + mt] = *(const bf16x8*)((ARD) + kk * 8192 + aro[mt]);          \
    CA_BODY(WH, CCX, AWR)                                                          \
    _Pragma("unroll") for (int kk = 0; kk < 2; ++kk)                               \
      _Pragma("unroll") for (int mt = 0; mt < 4; ++mt)                             \
        _Pragma("unroll") for (int nt = 0; nt < 4; ++nt)                           \
          acc[mt][nt] = __builtin_amdgcn_mfma_f32_16x16x32_bf16(                   \
              afr[kk * 4 + mt], BANK[kk * 4 + nt], acc[mt][nt], 0, 0, 0);          \
    __builtin_amdgcn_sched_group_barrier(0x20, 8, 0);   /* bank fill loads */      \
    __builtin_amdgcn_sched_group_barrier(0x100, 8, 0);  /* afr ds_reads   */       \
    _Pragma("unroll") for (int gq = 0; gq < 8; ++gq) {                             \
      __builtin_amdgcn_sched_group_barrier(0x2, 14, 0); /* conv VALU */            \
      __builtin_amdgcn_sched_group_barrier(0x8, 4, 0);  /* MFMA quad */            \
    }                                                                              \
    __builtin_amdgcn_sched_group_barrier(0x200, 2, 0);  /* A ds_writes */          \
    asm volatile("s_waitcnt lgkmcnt(0)" ::: "memory");                             \
    __builtin_amdgcn_sched_barrier(0);                                             \
    __builtin_amdgcn_s_barrier();                                                  \
    __builtin_amdgcn_sched_barrier(0);                                             \
  }

  bf16x8 bA[8], bB[8];

  // ---- prologue ----
  const Win wH0 = loadWin(0);
  const Win wH1 = loadWin(1);
  CC cc = loadCC(oh * 32);
#pragma unroll
  for (int nt = 0; nt < 4; ++nt) {
    bA[nt]     = *(gcbf16x8)(W1c + voff[nt]);
    bA[4 + nt] = *(gcbf16x8)(W1c + 16384 + voff[nt]);
  }
  CA_BODY(wH0, cc, smem)               // A(0) -> slot0
  asm volatile("s_waitcnt lgkmcnt(0)" ::: "memory");
  __builtin_amdgcn_sched_barrier(0);
  __builtin_amdgcn_s_barrier();
  __builtin_amdgcn_sched_barrier(0);

  const char* cb = W1c;
#pragma unroll 1
  for (int it = 0; it < 31; ++it) {
    CC ccN = loadCC(oh * 32 + it + 1);
    // ss even: mfma(slot0, bA); fill bB <- (oc, jg2/3); build A(ss+1)=(oc,h1) -> slot1
    CSTEP(smem, smem + 16384, bA, bB, cb + 32768, wH1, cc)
    // ss odd: mfma(slot1, bB); fill bA <- (oc+1, jg0/1); build A(ss+2)=(oc+1,h0) -> slot0
    CSTEP(smem + 16384, smem, bB, bA, cb + 524288, wH0, ccN)
    cc = ccN;
    cb += 524288;
  }
  // ---- peel ss=62: fill bB <- (o31, jg2/3); build A(63)=(o31,h1) -> slot1 ----
  CSTEP(smem, smem + 16384, bA, bB, cb + 32768, wH1, cc)
  // ---- ss=63: consume slot1 x bB (no fill / no A-gen / no barrier) ----
  {
    bf16x8 afr[8];
#pragma unroll
    for (int kk = 0; kk < 2; ++kk)
#pragma unroll
      for (int mt = 0; mt < 4; ++mt)
        afr[kk * 4 + mt] = *(const bf16x8*)(smem + 16384 + kk * 8192 + aro[mt]);
#pragma unroll
    for (int kk = 0; kk < 2; ++kk)
#pragma unroll
      for (int mt = 0; mt < 4; ++mt)
#pragma unroll
        for (int nt = 0; nt < 4; ++nt)
          acc[mt][nt] = __builtin_amdgcn_mfma_f32_16x16x32_bf16(
              afr[kk * 4 + mt], bB[kk * 4 + nt], acc[mt][nt], 0, 0, 0);
  }
#undef CSTEP
#undef CA_BODY

  // epilogue: split-K accumulate (16 partial adds per out element)
  const int rbase = b0 + wm * 64 + (lane >> 4) * 4;
  const int cbase = wvn * 64 + ln15;
#pragma unroll
  for (int mt = 0; mt < 4; ++mt)
#pragma unroll
    for (int nt = 0; nt < 4; ++nt)
#pragma unroll
      for (int r = 0; r < 4; ++r)
        atomicAdd(out1 + (size_t)(rbase + mt * 16 + r) * 256 + cbase + nt * 16,
                  acc[mt][nt][r]);
}

// ---------- final: bias+relu, fc2, node_feats, fc3 ----------
__global__ __launch_bounds__(512) void k_fin(const float* __restrict__ out1,
    const float* __restrict__ fc1_b, const float* __restrict__ fc2_W,
    const float* __restrict__ fc2_b, const float* __restrict__ fc3_W,
    const float* __restrict__ fc3_b, const int* __restrict__ src,
    const int* __restrict__ dst, const float* __restrict__ h2,
    const float* __restrict__ e2, float* __restrict__ outp) {
  int lane = threadIdx.x & 63, w = threadIdx.x >> 6;
  int b  = blockIdx.x * 8 + w;
  int bu = __builtin_amdgcn_readfirstlane(b);
  f32x4 o4 = ((const f32x4*)(out1 + (size_t)bu * 256))[lane];
  f32x4 bi = ((const f32x4*)fc1_b)[lane];
  float v[4];
#pragma unroll
  for (int r = 0; r < 4; ++r) v[r] = fmaxf(o4[r] + bi[r], 0.f);
  float a24[24];
#pragma unroll
  for (int q = 0; q < 24; ++q) a24[q] = 0.f;
#pragma unroll
  for (int r = 0; r < 4; ++r) {
    const float* wr = fc2_W + (size_t)(lane * 4 + r) * 24;
#pragma unroll
    for (int q = 0; q < 24; ++q) a24[q] = fmaf(v[r], wr[q], a24[q]);
  }
#pragma unroll
  for (int q = 0; q < 24; ++q) {
    float t = a24[q];
    t += __shfl_xor(t, 1);  t += __shfl_xor(t, 2);  t += __shfl_xor(t, 4);
    t += __shfl_xor(t, 8);  t += __shfl_xor(t, 16); t += __shfl_xor(t, 32);
    a24[q] = fmaxf(t + fc2_b[q], 0.f);
  }
  int s = src[bu], d2 = dst[bu];
  float nf[24];
#pragma unroll
  for (int q = 0; q < 8; ++q) {
    float hs = h2[(size_t)s * 8 + q];
    float hd = h2[(size_t)d2 * 8 + q];
    nf[q] = hs; nf[8 + q] = hd; nf[16 + q] = hs + hd + e2[(size_t)bu * 8 + q];
  }
  if (lane == 0) {
#pragma unroll
    for (int c = 0; c < 2; ++c) {
      float r = fc3_b[c];
#pragma unroll
      for (int q = 0; q < 24; ++q) r = fmaf(a24[q], fc3_W[q * 2 + c], r);
#pragma unroll
      for (int q = 0; q < 24; ++q) r = fmaf(nf[q], fc3_W[(24 + q) * 2 + c], r);
      outp[(size_t)bu * 2 + c] = r;
    }
  }
}

// ---------- launch ----------
extern "C" void kernel_launch(void* const* d_in, const int* in_sizes, int n_in,
                              void* d_out, int out_size, void* d_ws, size_t ws_size,
                              hipStream_t stream) {
  const float* X         = (const float*)d_in[0];
  const int*   src       = (const int*)d_in[1];
  const int*   dst       = (const int*)d_in[2];
  const float* node_feat = (const float*)d_in[3];
  const float* edge_feat = (const float*)d_in[4];
  const float* attn_W    = (const float*)d_in[5];
  const float* attn_U    = (const float*)d_in[6];
  const float* attn_V    = (const float*)d_in[7];
  const float* conv_w    = (const float*)d_in[8];
  const float* conv_b    = (const float*)d_in[9];
  const float* gc1_W     = (const float*)d_in[10];
  const float* gc1_b     = (const float*)d_in[11];
  const float* gc2_W     = (const float*)d_in[12];
  const float* gc2_b     = (const float*)d_in[13];
  const float* lin1_W    = (const float*)d_in[14];
  const float* lin1_b    = (const float*)d_in[15];
  const float* lin2_W    = (const float*)d_in[16];
  const float* lin2_b    = (const float*)d_in[17];
  const float* fc1_W     = (const float*)d_in[18];
  const float* fc1_b     = (const float*)d_in[19];
  const float* fc2_W     = (const float*)d_in[20];
  const float* fc2_b     = (const float*)d_in[21];
  const float* fc3_W     = (const float*)d_in[22];
  const float* fc3_b     = (const float*)d_in[23];

  char* ws = (char*)d_ws;
  float*    out1 = (float*)(ws + 0);               // 4096*256*4      = 4,194,304
  float*    agg1 = (float*)(ws + 4194304);         // 2048*128*4      = 1,048,576
  float*    agg2 = (float*)(ws + 5242880);         // 2048*128*4      = 1,048,576
  float*    degO = (float*)(ws + 6291456);         // 2048*4
  float*    degI = (float*)(ws + 6299648);         // 2048*4
  uint16_t* W1s  = (uint16_t*)(ws + 6307840);      // 65536*256*2     = 33,554,432
  uint16_t* att  = (uint16_t*)(ws + 39862272);     // 4096*9*136*2    = 10,027,008
  float*    h1   = (float*)(ws + 49889280);        // 2048*128*4
  float*    h2   = (float*)(ws + 50937856);        // 2048*8*4
  float*    e2   = (float*)(ws + 51003392);        // 4096*8*4

  hipMemsetAsync(d_ws, 0, 6307840, stream);        // out1, agg1, agg2, degs

  k_prep<<<dim3(2048), dim3(256), 0, stream>>>(fc1_W, W1s);
  k_att <<<dim3(256),  dim3(512), 0, stream>>>(X, attn_W, attn_U, attn_V, att);
  k_deg <<<dim3(16),   dim3(256), 0, stream>>>(src, dst, degO, degI);
  k_gca <<<dim3(2048), dim3(256), 0, stream>>>(node_feat, src, dst, degO, agg1);
  k_gc1b<<<dim3(2048), dim3(128), 0, stream>>>(agg1, degI, gc1_W, gc1_b, h1);
  k_gca <<<dim3(2048), dim3(256), 0, stream>>>(h1, src, dst, degO, agg2);
  k_gc2b<<<dim3(2048), dim3(128), 0, stream>>>(agg2, degI, gc2_W, gc2_b, h2);
  k_e12 <<<dim3(256),  dim3(128), 0, stream>>>(edge_feat, lin1_W, lin1_b, lin2_W, lin2_b, e2);
  k_gemm<<<dim3(512),  dim3(512), 0, stream>>>(W1s, att, conv_w, conv_b, out1);
  k_fin <<<dim3(512),  dim3(512), 0, stream>>>(out1, fc1_b, fc2_W, fc2_b, fc3_W, fc3_b,
                                               src, dst, h2, e2, (float*)d_out);
}